// Round 4
// baseline (2012.189 us; speedup 1.0000x reference)
//
#include <hip/hip_runtime.h>
#include <cstddef>
#include <cstdint>

// ---------------------------------------------------------------------------
// FCGCN — R4: everything fits in 205.3 MB of workspace (R1/R2/R3 used
// 521/387/269 MB and all hard-aborted; R3's tail started at exactly 256 MiB,
// so ws_size==256MiB explains all three faults). Key changes:
//  * FC3 and GCN1 are IN-PLACE row-stripe kernels (row-local GEMMs): the
//    h2/h3/out1 chain lives in ONE 134 MB buffer.
//  * gram computed in 4 row-chunks: transpose chunk into 33.5 MB scratch
//    (overlays dead h1), split-K gemm accumulating into per-z fp32 partials
//    (sequential launches -> no race), then reduce.
//  * ws_size gate: if ws_size < NEED, zero d_out and return (clean absmax
//    failure instead of an abort = diagnostic for the ws theory).
// Algebra: S folded into GW1/GW2 (saves ~275 GFLOP); BN biases cancel.
// ---------------------------------------------------------------------------

typedef unsigned short u16;
typedef unsigned int   u32;
typedef __attribute__((ext_vector_type(8))) short  s16x8;
typedef __attribute__((ext_vector_type(4))) float  f32x4;
typedef __attribute__((ext_vector_type(4))) u16    u16x4;
typedef __attribute__((ext_vector_type(2))) u16    u16x2;

__device__ __forceinline__ float b2f(u16 u){ u32 x = ((u32)u)<<16; float f; __builtin_memcpy(&f,&x,4); return f; }
__device__ __forceinline__ u16 f2b(float f){ u32 x; __builtin_memcpy(&x,&f,4); x += 0x7fffu + ((x>>16)&1u); return (u16)(x>>16); }

// ---------------------------------------------------------------------------
// gemm128: C[M,N] = A[M,K] @ Bt[N,K]^T (row-major, K contiguous). 128x128
// tile, BK=64, 256 thr = 4 waves (2x2), each wave 64x64 = 4x4 16x16x32 frags.
// Register staging (global->reg->ds_write_b128), no async LDS.
// AF32: A operand fp32, converted during staging (FC1 reads x directly).
// EPI: 0 bf16 store; 1 bf16 relu(v+bias[col]); 2 fp32 "+=" into per-z
//      partial (race-free: one tile owner per launch, z-planes disjoint);
//      3 bf16 transposed store (C^T).
// ---------------------------------------------------------------------------
template<int EPI, int AF32>
__global__ __launch_bounds__(256)
void gemm128(const void* __restrict__ Ap, const u16* __restrict__ Bt,
             void* __restrict__ Cout, const float* __restrict__ bias,
             int M, int Nn, int ksz, int lda, int ldb, int ldc, int lgn)
{
  __shared__ u16 lAs[128*64];
  __shared__ u16 lBs[128*64];
  const int tid  = threadIdx.x;
  const int wid  = tid >> 6;
  const int lane = tid & 63;

  const int nwg  = gridDim.x;
  const int bid  = blockIdx.x;
  const int swz  = (bid & 7) * (nwg >> 3) + (bid >> 3);   // XCD-chunked
  const int nblk = swz & ((1 << lgn) - 1);
  const int mblk = swz >> lgn;
  const int k0   = blockIdx.z * ksz;

  f32x4 acc[4][4];
#pragma unroll
  for (int i = 0; i < 4; ++i)
#pragma unroll
    for (int j = 0; j < 4; ++j) acc[i][j] = (f32x4){0.f,0.f,0.f,0.f};

  const u16*   A16 = (const u16*)Ap   + (size_t)mblk*128*lda + k0;
  const float* A32 = (const float*)Ap + (size_t)mblk*128*lda + k0;
  const u16* Bbase = Bt + (size_t)nblk*128*ldb + k0;
  const int wm = wid >> 1, wn = wid & 1;
  const int lr = lane & 15, lk = (lane >> 4) * 8;
  const u16* lA = &lAs[wm*64*64];
  const u16* lB = &lBs[wn*64*64];
  const int srow = tid >> 3;
  const int scol = (tid & 7) * 8;

  const int nkt = ksz >> 6;
  for (int kt = 0; kt < nkt; ++kt) {
    s16x8 ar[4], br[4];
#pragma unroll
    for (int i = 0; i < 4; ++i) {
      const size_t ro = (size_t)(i*32 + srow);
      if (AF32) {
        const float* p = A32 + ro*lda + kt*64 + scol;
        f32x4 x0 = *(const f32x4*)p;
        f32x4 x1 = *(const f32x4*)(p + 4);
        s16x8 v;
        v[0]=(short)f2b(x0[0]); v[1]=(short)f2b(x0[1]);
        v[2]=(short)f2b(x0[2]); v[3]=(short)f2b(x0[3]);
        v[4]=(short)f2b(x1[0]); v[5]=(short)f2b(x1[1]);
        v[6]=(short)f2b(x1[2]); v[7]=(short)f2b(x1[3]);
        ar[i] = v;
      } else {
        ar[i] = *(const s16x8*)(A16 + ro*lda + kt*64 + scol);
      }
      br[i] = *(const s16x8*)(Bbase + ro*ldb + kt*64 + scol);
    }
    __syncthreads();
#pragma unroll
    for (int i = 0; i < 4; ++i) {
      *(s16x8*)&lAs[i*2048 + tid*8] = ar[i];
      *(s16x8*)&lBs[i*2048 + tid*8] = br[i];
    }
    __syncthreads();
#pragma unroll
    for (int kk = 0; kk < 64; kk += 32) {
      s16x8 af[4], bf[4];
#pragma unroll
      for (int mi = 0; mi < 4; ++mi) af[mi] = *(const s16x8*)(lA + (mi*16+lr)*64 + kk + lk);
#pragma unroll
      for (int ni = 0; ni < 4; ++ni) bf[ni] = *(const s16x8*)(lB + (ni*16+lr)*64 + kk + lk);
#pragma unroll
      for (int mi = 0; mi < 4; ++mi)
#pragma unroll
        for (int ni = 0; ni < 4; ++ni)
          acc[mi][ni] = __builtin_amdgcn_mfma_f32_16x16x32_bf16(af[mi], bf[ni], acc[mi][ni], 0, 0, 0);
    }
  }

  // C/D frag: col = lane&15, row = (lane>>4)*4 + reg  [m91-verified]
  const int r0 = mblk*128 + wm*64;
  const int c0 = nblk*128 + wn*64;
  const int rr = (lane >> 4) * 4;

  if (EPI == 2) {
    float* Cp = (float*)Cout + (size_t)blockIdx.z * (size_t)M * (size_t)Nn;
#pragma unroll
    for (int mi = 0; mi < 4; ++mi)
#pragma unroll
      for (int ni = 0; ni < 4; ++ni)
#pragma unroll
        for (int r = 0; r < 4; ++r) {
          size_t idx = (size_t)(r0 + mi*16 + rr + r)*ldc + (c0 + ni*16 + lr);
          Cp[idx] += acc[mi][ni][r];
        }
  } else if (EPI == 3) {
    u16* Cp = (u16*)Cout;
#pragma unroll
    for (int mi = 0; mi < 4; ++mi)
#pragma unroll
      for (int ni = 0; ni < 4; ++ni)
#pragma unroll
        for (int r = 0; r < 4; ++r)
          Cp[(size_t)(c0 + ni*16 + lr)*ldc + (r0 + mi*16 + rr + r)] = f2b(acc[mi][ni][r]);
  } else {
    u16* Cp = (u16*)Cout;
    float bv[4];
#pragma unroll
    for (int ni = 0; ni < 4; ++ni)
      bv[ni] = (EPI == 1 && bias) ? bias[c0 + ni*16 + lr] : 0.f;
#pragma unroll
    for (int mi = 0; mi < 4; ++mi)
#pragma unroll
      for (int ni = 0; ni < 4; ++ni)
#pragma unroll
        for (int r = 0; r < 4; ++r) {
          float v = acc[mi][ni][r];
          if (EPI == 1) v = fmaxf(v + bv[ni], 0.f);
          Cp[(size_t)(r0 + mi*16 + rr + r)*ldc + (c0 + ni*16 + lr)] = f2b(v);
        }
  }
  (void)M; (void)Nn;
}

// ---------------------------------------------------------------------------
// In-place row-local GEMM: for each 64-row stripe of X [65536][1024]:
//   X_stripe = relu(X_stripe @ W + bias),  W given as Bt [1024 outcol][1024 k].
// Block = 512 thr (8 waves, 2x4), stripe staged in 128 KB LDS (XOR-swizzled
// col ^= (row&7)<<3 to break the 16-way ds_read_b128 conflict), then the
// stripe's global rows are overwritten. Row-exclusive per block => race-free.
// ---------------------------------------------------------------------------
__global__ __launch_bounds__(512, 2)
void rowgemm_inplace(u16* __restrict__ X, const u16* __restrict__ Bt,
                     const float* __restrict__ bias)
{
  __shared__ u16 ls[64*1024];          // 128 KB
  const int tid  = threadIdx.x;        // 0..511
  const int wid  = tid >> 6;           // 0..7
  const int lane = tid & 63;
  const size_t row0 = (size_t)blockIdx.x * 64;

  // stage stripe (swizzled)
  const u16* src = X + row0*1024;
#pragma unroll
  for (int i = 0; i < 16; ++i) {
    int idx = i*4096 + tid*8;
    int row = idx >> 10, col = idx & 1023;
    s16x8 v = *(const s16x8*)(src + idx);
    *(s16x8*)&ls[(row<<10) + (col ^ ((row&7)<<3))] = v;
  }
  __syncthreads();

  const int lr = lane & 15, lk = (lane >> 4)*8;
  const int arow0 = (wid >> 2) * 32;   // wave rows: 32
  const int bcol0 = (wid & 3) * 256;   // wave cols: 256

  f32x4 acc[2][16];
#pragma unroll
  for (int mi = 0; mi < 2; ++mi)
#pragma unroll
    for (int j = 0; j < 16; ++j) acc[mi][j] = (f32x4){0.f,0.f,0.f,0.f};

  const int rowA0 = arow0 + lr;        // mi adds 16
  const int swz0  = ((rowA0      & 7) << 3);
  const int swz1  = (((rowA0+16) & 7) << 3);   // == swz0 (16 preserves &7)

  for (int kk = 0; kk < 1024; kk += 32) {
    s16x8 af[2];
    af[0] = *(const s16x8*)&ls[((rowA0   )<<10) + ((kk+lk) ^ swz0)];
    af[1] = *(const s16x8*)&ls[((rowA0+16)<<10) + ((kk+lk) ^ swz1)];
#pragma unroll
    for (int g = 0; g < 4; ++g) {
      s16x8 bf[4];
#pragma unroll
      for (int ni = 0; ni < 4; ++ni)
        bf[ni] = *(const s16x8*)(Bt + (size_t)(bcol0 + g*64 + ni*16 + lr)*1024 + kk + lk);
#pragma unroll
      for (int mi = 0; mi < 2; ++mi)
#pragma unroll
        for (int ni = 0; ni < 4; ++ni)
          acc[mi][g*4+ni] = __builtin_amdgcn_mfma_f32_16x16x32_bf16(af[mi], bf[ni], acc[mi][g*4+ni], 0, 0, 0);
    }
  }

  // write back over own stripe (C/D: col=lane&15, row=(lane>>4)*4+r)
  const int rr = (lane >> 4) * 4;
#pragma unroll
  for (int mi = 0; mi < 2; ++mi)
#pragma unroll
    for (int g = 0; g < 4; ++g)
#pragma unroll
      for (int ni = 0; ni < 4; ++ni) {
        const int col = bcol0 + g*64 + ni*16 + lr;
        const float bv = bias ? bias[col] : 0.f;
#pragma unroll
        for (int r = 0; r < 4; ++r) {
          const int row = arow0 + mi*16 + rr + r;
          X[(row0 + row)*1024 + col] = f2b(fmaxf(acc[mi][g*4+ni][r] + bv, 0.f));
        }
      }
}

// --------------------------- prep / elementwise ----------------------------

__global__ void zero_f32(float* __restrict__ p, int n)
{
  int i = blockIdx.x*256 + threadIdx.x;
  if (i < n) p[i] = 0.f;
}

// W [R,C] fp32 -> Wt [C,R] bf16
__global__ void transpose_cvt(const float* __restrict__ in, u16* __restrict__ out, int R, int C)
{
  __shared__ float t[32][33];
  const int bc = blockIdx.x*32, br = blockIdx.y*32;
  const int tx = threadIdx.x & 31, ty = threadIdx.x >> 5;
#pragma unroll
  for (int i = 0; i < 4; ++i) t[ty + 8*i][tx] = in[(size_t)(br + ty + 8*i)*C + bc + tx];
  __syncthreads();
#pragma unroll
  for (int i = 0; i < 4; ++i) out[(size_t)(bc + ty + 8*i)*R + br + tx] = f2b(t[tx][ty + 8*i]);
}

// per-column sum/sumsq of bf16 [rows, C]
__global__ void col_stats(const u16* __restrict__ X, float* __restrict__ sum,
                          float* __restrict__ sumsq, int C, int rpb)
{
  const int t = threadIdx.x;
  const int vc = C >> 8;
  const size_t r0 = (size_t)blockIdx.x * rpb;
  const int c0 = t * vc;
  float s[4] = {0,0,0,0}, q[4] = {0,0,0,0};
  if (vc == 4) {
    for (int r = 0; r < rpb; ++r) {
      u16x4 v = *(const u16x4*)(X + (r0 + r)*C + c0);
#pragma unroll
      for (int j = 0; j < 4; ++j) { float f = b2f(v[j]); s[j] += f; q[j] += f*f; }
    }
  } else {
    for (int r = 0; r < rpb; ++r) {
      u16x2 v = *(const u16x2*)(X + (r0 + r)*C + c0);
#pragma unroll
      for (int j = 0; j < 2; ++j) { float f = b2f(v[j]); s[j] += f; q[j] += f*f; }
    }
  }
  for (int j = 0; j < vc; ++j) {
    atomicAdd(&sum[c0 + j],   s[j]);
    atomicAdd(&sumsq[c0 + j], q[j]);
  }
}

__global__ void bn_finalize(const float* __restrict__ sum, const float* __restrict__ sumsq,
                            const float* __restrict__ g, const float* __restrict__ be,
                            float* __restrict__ a, float* __restrict__ b, int C, float invN)
{
  int c = blockIdx.x*256 + threadIdx.x;
  if (c < C) {
    float mu  = sum[c]*invN;
    float var = sumsq[c]*invN - mu*mu;
    float ac  = g[c]*rsqrtf(var + 1e-5f);
    a[c] = ac;
    b[c] = be[c] - mu*ac;
  }
}

__global__ void bn_apply(u16* __restrict__ X, const float* __restrict__ a,
                         const float* __restrict__ b, size_t n8, int cmask)
{
  size_t i0 = (size_t)blockIdx.x*blockDim.x + threadIdx.x;
  size_t str = (size_t)gridDim.x*blockDim.x;
  for (size_t v = i0; v < n8; v += str) {
    size_t base = v*8;
    int c0 = (int)(base & (size_t)cmask);
    s16x8 x = *(const s16x8*)(X + base);
    s16x8 y;
#pragma unroll
    for (int j = 0; j < 8; ++j) {
      float f = b2f((u16)x[j]) * a[c0 + j] + b[c0 + j];
      y[j] = (short)f2b(fmaxf(f, 0.f));
    }
    *(s16x8*)(X + base) = y;
  }
}

// bf16 [R,C] -> [C,R]
__global__ void transpose_bf16(const u16* __restrict__ in, u16* __restrict__ out, int R, int C)
{
  __shared__ u16 t[64][72];
  const int r0 = blockIdx.x*64, c0 = blockIdx.y*64;
  const int tid = threadIdx.x;
#pragma unroll
  for (int i = 0; i < 2; ++i) {
    int v = i*256 + tid;
    int r = v >> 3, c8 = (v & 7)*8;
    *(s16x8*)&t[r][c8] = *(const s16x8*)&in[(size_t)(r0 + r)*C + c0 + c8];
  }
  __syncthreads();
#pragma unroll
  for (int i = 0; i < 2; ++i) {
    int v = i*256 + tid;
    int c = v >> 3, r8 = (v & 7)*8;
    s16x8 o;
#pragma unroll
    for (int j = 0; j < 8; ++j) o[j] = (short)t[r8 + j][c];
    *(s16x8*)&out[(size_t)(c0 + c)*R + r0 + r8] = o;
  }
}

__global__ void reduce_part(const float* __restrict__ P, float* __restrict__ G, int n, int parts)
{
  int e = blockIdx.x*256 + threadIdx.x;
  if (e < n) {
    float s = 0.f;
    for (int p = 0; p < parts; ++p) s += P[(size_t)p*n + e];
    G[e] = s;
  }
}

__global__ void k_norms(const float* __restrict__ gram, float* __restrict__ norms)
{
  int i = blockIdx.x*256 + threadIdx.x;
  if (i < 1024) norms[i] = sqrtf(fmaxf(gram[(size_t)i*1025], 0.f));
}

__global__ void k_degree(const float* __restrict__ gram, const float* __restrict__ norms,
                         float* __restrict__ dinv)
{
  const int i = blockIdx.x, t = threadIdx.x;
  const float ni = norms[i];
  float p = 0.f;
  for (int j = t; j < 1024; j += 256)
    p += gram[(size_t)i*1024 + j] / (ni*norms[j] + 1e-10f);
#pragma unroll
  for (int o = 32; o; o >>= 1) p += __shfl_down(p, o, 64);
  __shared__ float ws[4];
  if ((t & 63) == 0) ws[t >> 6] = p;
  __syncthreads();
  if (t == 0) {
    float d = ws[0] + ws[1] + ws[2] + ws[3] + 1.0f;
    dinv[i] = d > 0.f ? rsqrtf(d) : 0.f;
  }
}

__global__ void k_sbuild(const float* __restrict__ gram, const float* __restrict__ norms,
                         const float* __restrict__ dinv, u16* __restrict__ Sb)
{
  int e = blockIdx.x*256 + threadIdx.x;
  int i = e >> 10, j = e & 1023;
  float adj = gram[e] / (norms[i]*norms[j] + 1e-10f);
  float a = adj + (i == j ? 1.f : 0.f);
  Sb[e] = f2b(dinv[i]*a*dinv[j]);
}

// SG2T[j,i] = sum_m S[i,m]*GW2[m,j]  (bf16 [16,1024])
__global__ void k_sg2t(const u16* __restrict__ SB, const float* __restrict__ GW2,
                       u16* __restrict__ SG2T)
{
  const int t = threadIdx.x;
  const int i = blockIdx.x*16 + (t >> 4);
  const int j = t & 15;
  float acc = 0.f;
  for (int m = 0; m < 1024; ++m) acc += b2f(SB[(size_t)i*1024 + m]) * GW2[m*16 + j];
  SG2T[j*1024 + i] = f2b(acc);
}

// out[N,16] = relu(out1 @ SG2T^T), one 16x16 tile per wave, K=1024
__global__ __launch_bounds__(256)
void k_final(const u16* __restrict__ A, const u16* __restrict__ Bt, float* __restrict__ out)
{
  const int wid = threadIdx.x >> 6, lane = threadIdx.x & 63;
  const int r0 = (blockIdx.x*4 + wid) * 16;
  const int lr = lane & 15, lk = (lane >> 4)*8;
  f32x4 acc = (f32x4){0.f,0.f,0.f,0.f};
  const u16* Ab = A  + (size_t)(r0 + lr)*1024 + lk;
  const u16* Bb = Bt + (size_t)lr*1024 + lk;
#pragma unroll 4
  for (int k = 0; k < 1024; k += 32) {
    s16x8 a = *(const s16x8*)(Ab + k);
    s16x8 b = *(const s16x8*)(Bb + k);
    acc = __builtin_amdgcn_mfma_f32_16x16x32_bf16(a, b, acc, 0, 0, 0);
  }
  const int col = lane & 15;
  const int rbase = r0 + (lane >> 4)*4;
#pragma unroll
  for (int r = 0; r < 4; ++r)
    out[(size_t)(rbase + r)*16 + col] = fmaxf(acc[r], 0.f);
}

// ---------------------------------------------------------------------------

extern "C" void kernel_launch(void* const* d_in, const int* in_sizes, int n_in,
                              void* d_out, int out_size, void* d_ws, size_t ws_size,
                              hipStream_t stream)
{
  const float* x   = (const float*)d_in[0];
  const float* W1  = (const float*)d_in[1];
  const float* g1  = (const float*)d_in[3];
  const float* be1 = (const float*)d_in[4];
  const float* W2  = (const float*)d_in[5];
  const float* g2  = (const float*)d_in[7];
  const float* be2 = (const float*)d_in[8];
  const float* W3  = (const float*)d_in[9];
  const float* b3  = (const float*)d_in[10];
  const float* GW1 = (const float*)d_in[11];
  const float* GW2 = (const float*)d_in[12];
  float* outp = (float*)d_out;

  // ---- workspace layout, peak 205.3 MB ----
  // [0,128M)      hbuf: h2 -> h3 (in-place FC3) -> out1 (in-place GCN1)
  // [128M,192M)   h1 (dead after FC2); then h3t chunk (33.5M) + part (16.8M)
  // [192M,205.3M) weights + GRAM + stats
  const size_t NEED = 215277568ull;
  if (ws_size < NEED) {                  // diagnostic fallback: clean fail
    zero_f32<<<4096, 256, 0, stream>>>((float*)d_out, 1048576);
    return;
  }
  char* w = (char*)d_ws;
  u16*   hbuf = (u16*)(w);                       // 134,217,728
  u16*   h1   = (u16*)(w + 134217728ull);        //  67,108,864
  u16*   h3t  = (u16*)(w + 134217728ull);        //  33,554,432 (over dead h1)
  float* part = (float*)(w + 167772160ull);      //  16,777,216 (4 z-planes)
  u16*   W1T  = (u16*)(w + 201326592ull);
  u16*   W2T  = (u16*)(w + 201588736ull);
  u16*   W3T  = (u16*)(w + 202637312ull);
  u16*   GW1T = (u16*)(w + 204734464ull);
  u16*   SB   = (u16*)(w + 206831616ull);
  u16*   SG1T = (u16*)(w + 208928768ull);
  u16*   SG2T = (u16*)(w + 211025920ull);
  float* GRAM = (float*)(w + 211058688ull);
  float* NORMS= (float*)(w + 215252992ull);
  float* DINV = (float*)(w + 215257088ull);
  float* BNS  = (float*)(w + 215261184ull);
  float* BNQ  = (float*)(w + 215265280ull);
  float* BNA  = (float*)(w + 215269376ull);
  float* BNB  = (float*)(w + 215273472ull);      // end = 215,277,568

  // weight prep
  transpose_cvt<<<dim3(16, 8),  256, 0, stream>>>(W1,  W1T,  256, 512);
  transpose_cvt<<<dim3(32, 16), 256, 0, stream>>>(W2,  W2T,  512, 1024);
  transpose_cvt<<<dim3(32, 32), 256, 0, stream>>>(W3,  W3T,  1024, 1024);
  transpose_cvt<<<dim3(32, 32), 256, 0, stream>>>(GW1, GW1T, 1024, 1024);

  // FC1 (fp32 x) + BN1 + ReLU
  gemm128<0,1><<<dim3(2048,1,1), 256, 0, stream>>>(x, W1T, h1, nullptr,
      65536, 512, 256, 256, 256, 512, 2);
  zero_f32<<<8, 256, 0, stream>>>(BNS, 2048);
  col_stats<<<512, 256, 0, stream>>>(h1, BNS, BNQ, 512, 128);
  bn_finalize<<<2, 256, 0, stream>>>(BNS, BNQ, g1, be1, BNA, BNB, 512, 1.f/65536.f);
  bn_apply<<<2048, 256, 0, stream>>>(h1, BNA, BNB, 4194304ull, 511);

  // FC2 + BN2 + ReLU -> hbuf
  gemm128<0,0><<<dim3(4096,1,1), 256, 0, stream>>>(h1, W2T, hbuf, nullptr,
      65536, 1024, 512, 512, 512, 1024, 3);
  zero_f32<<<8, 256, 0, stream>>>(BNS, 2048);
  col_stats<<<512, 256, 0, stream>>>(hbuf, BNS, BNQ, 1024, 128);
  bn_finalize<<<4, 256, 0, stream>>>(BNS, BNQ, g2, be2, BNA, BNB, 1024, 1.f/65536.f);
  bn_apply<<<2048, 256, 0, stream>>>(hbuf, BNA, BNB, 8388608ull, 1023);

  // FC3 + bias + ReLU, IN-PLACE: hbuf (h2) -> hbuf (h3)
  rowgemm_inplace<<<1024, 512, 0, stream>>>(hbuf, W3T, b3);

  // gram = h3^T h3, 4 row-chunks of 16384, split-K z=4 into part planes
  zero_f32<<<16384, 256, 0, stream>>>(part, 4194304);
  for (int c = 0; c < 4; ++c) {
    transpose_bf16<<<dim3(256, 16), 256, 0, stream>>>(hbuf + (size_t)c*16384*1024, h3t, 16384, 1024);
    gemm128<2,0><<<dim3(64,1,4), 256, 0, stream>>>(h3t, h3t, part, nullptr,
        1024, 1024, 4096, 16384, 16384, 1024, 3);
  }
  reduce_part<<<4096, 256, 0, stream>>>(part, GRAM, 1048576, 4);

  // S build + folded weights
  k_norms<<<4, 256, 0, stream>>>(GRAM, NORMS);
  k_degree<<<1024, 256, 0, stream>>>(GRAM, NORMS, DINV);
  k_sbuild<<<4096, 256, 0, stream>>>(GRAM, NORMS, DINV, SB);
  k_sg2t<<<64, 256, 0, stream>>>(SB, GW2, SG2T);
  gemm128<3,0><<<dim3(64,1,1), 256, 0, stream>>>(SB, GW1T, SG1T, nullptr,
      1024, 1024, 1024, 1024, 1024, 1024, 3);

  // GCN layer 1, IN-PLACE: hbuf (h3) -> hbuf (out1)
  rowgemm_inplace<<<1024, 512, 0, stream>>>(hbuf, SG1T, nullptr);

  // GCN layer 2: out = relu(out1 @ SG2)
  k_final<<<1024, 256, 0, stream>>>(hbuf, SG2T, outp);

  (void)in_sizes; (void)n_in; (void)out_size;
}

// Round 5
// 1631.968 us; speedup vs baseline: 1.2330x; 1.2330x over previous
//
#include <hip/hip_runtime.h>
#include <cstddef>
#include <cstdint>

// ---------------------------------------------------------------------------
// FCGCN — R5. R4 passed (2012 µs); rowgemm_inplace was 53% of time and
// latency-bound on per-wave B loads from L2 (MfmaUtil 10.6%). Changes:
//  * rowgemm2: cooperative B-tile LDS double-buffer staged via
//    global_load_lds (pre-swizzled source), XOR-swizzled reads; per-col-tile
//    epilogue stores (input is in LDS -> in-place still race-free).
//  * BN1/BN2 application fused into the consuming GEMM's A-staging
//    (bn_apply kernels deleted; stats still computed on raw activations).
//  * global_load_lds reinstated in gemm128 (R3/R4 exonerated it; faults
//    were workspace overflow past 256 MiB).
//  * ws_size probe: big layout (>=350 MB) does FC3/GCN1 as out-of-place
//    gemm128; else the R4-proven 215 MB layout with rowgemm2.
// Algebra: S folded into GW1/GW2; BN biases b1,b2 cancel and are never read.
// ---------------------------------------------------------------------------

typedef unsigned short u16;
typedef unsigned int   u32;
typedef __attribute__((ext_vector_type(8))) short  s16x8;
typedef __attribute__((ext_vector_type(4))) float  f32x4;
typedef __attribute__((ext_vector_type(4))) u16    u16x4;
typedef __attribute__((ext_vector_type(2))) u16    u16x2;

__device__ __forceinline__ float b2f(u16 u){ u32 x = ((u32)u)<<16; float f; __builtin_memcpy(&f,&x,4); return f; }
__device__ __forceinline__ u16 f2b(float f){ u32 x; __builtin_memcpy(&x,&f,4); x += 0x7fffu + ((x>>16)&1u); return (u16)(x>>16); }

typedef const __attribute__((address_space(1))) u32* gas1_t;
typedef __attribute__((address_space(3))) u32*       las3_t;
__device__ __forceinline__ void gld_lds16(const void* g, void* l){
  // async global->LDS: per-lane global src, wave-uniform LDS base + lane*16.
  __builtin_amdgcn_global_load_lds((gas1_t)g, (las3_t)l, 16, 0, 0);
}

// ---------------------------------------------------------------------------
// gemm128: C[M,N] = A[M,K] @ Bt[N,K]^T (row-major, K contiguous). 128x128
// tile, BK=64, 256 thr = 4 waves (2x2), each wave 64x64 = 4x4 16x16x32 frags.
// B staged via global_load_lds (width 16). A per AMODE:
//   0: bf16 via global_load_lds; 1: fp32->bf16 cvt (reg path);
//   2: bf16 with fused y=relu(v*as_[k]+bs_[k]) (reg path).
// EPI: 0 bf16 store; 1 bf16 relu(v+bias[col]); 2 fp32 += into z-plane
//      partial (sequential accumulation); 3 bf16 transposed store (C^T).
// ---------------------------------------------------------------------------
template<int EPI, int AMODE>
__global__ __launch_bounds__(256)
void gemm128(const void* __restrict__ Ap, const u16* __restrict__ Bt,
             void* __restrict__ Cout, const float* __restrict__ bias,
             const float* __restrict__ as_, const float* __restrict__ bs_,
             int M, int Nn, int ksz, int lda, int ldb, int ldc, int lgn)
{
  __shared__ u16 lAs[128*64];
  __shared__ u16 lBs[128*64];
  const int tid = threadIdx.x, wid = tid >> 6, lane = tid & 63;

  const int nwg  = gridDim.x;
  const int bid  = blockIdx.x;
  const int swz  = (bid & 7) * (nwg >> 3) + (bid >> 3);   // XCD-chunked
  const int nblk = swz & ((1 << lgn) - 1);
  const int mblk = swz >> lgn;
  const int k0   = blockIdx.z * ksz;

  f32x4 acc[4][4];
#pragma unroll
  for (int i = 0; i < 4; ++i)
#pragma unroll
    for (int j = 0; j < 4; ++j) acc[i][j] = (f32x4){0.f,0.f,0.f,0.f};

  const u16*   A16 = (const u16*)Ap   + (size_t)mblk*128*lda + k0;
  const float* A32 = (const float*)Ap + (size_t)mblk*128*lda + k0;
  const u16* Bbase = Bt + (size_t)nblk*128*ldb + k0;
  const int wm = wid >> 1, wn = wid & 1;
  const int lr = lane & 15, lk = (lane >> 4) * 8;
  const u16* lA = &lAs[wm*64*64];
  const u16* lB = &lBs[wn*64*64];
  const int srow = tid >> 3;          // 32 rows per issue, 8 threads/row
  const int scol = (tid & 7) * 8;     // 8 bf16 = 16B per thread

  const int nkt = ksz >> 6;
  for (int kt = 0; kt < nkt; ++kt) {
    __syncthreads();                  // all waves done with prev tile's LDS
    const u16* Bk = Bbase + kt*64;
#pragma unroll
    for (int i = 0; i < 4; ++i)
      gld_lds16(Bk + (size_t)(i*32 + srow)*ldb + scol, &lBs[i*2048 + wid*512]);
    if (AMODE == 0) {
      const u16* Ak = A16 + kt*64;
#pragma unroll
      for (int i = 0; i < 4; ++i)
        gld_lds16(Ak + (size_t)(i*32 + srow)*lda + scol, &lAs[i*2048 + wid*512]);
    } else if (AMODE == 1) {
#pragma unroll
      for (int i = 0; i < 4; ++i) {
        const float* p = A32 + (size_t)(i*32 + srow)*lda + kt*64 + scol;
        f32x4 x0 = *(const f32x4*)p;
        f32x4 x1 = *(const f32x4*)(p + 4);
        s16x8 v;
        v[0]=(short)f2b(x0[0]); v[1]=(short)f2b(x0[1]);
        v[2]=(short)f2b(x0[2]); v[3]=(short)f2b(x0[3]);
        v[4]=(short)f2b(x1[0]); v[5]=(short)f2b(x1[1]);
        v[6]=(short)f2b(x1[2]); v[7]=(short)f2b(x1[3]);
        *(s16x8*)&lAs[i*2048 + tid*8] = v;
      }
    } else {                          // AMODE 2: fused BN+relu on A cols (=k)
      const int cb = k0 + kt*64 + scol;
      f32x4 a0 = *(const f32x4*)(as_ + cb), a1 = *(const f32x4*)(as_ + cb + 4);
      f32x4 b0 = *(const f32x4*)(bs_ + cb), b1 = *(const f32x4*)(bs_ + cb + 4);
#pragma unroll
      for (int i = 0; i < 4; ++i) {
        s16x8 r = *(const s16x8*)(A16 + (size_t)(i*32 + srow)*lda + kt*64 + scol);
        s16x8 v;
        v[0]=(short)f2b(fmaxf(b2f((u16)r[0])*a0[0]+b0[0],0.f));
        v[1]=(short)f2b(fmaxf(b2f((u16)r[1])*a0[1]+b0[1],0.f));
        v[2]=(short)f2b(fmaxf(b2f((u16)r[2])*a0[2]+b0[2],0.f));
        v[3]=(short)f2b(fmaxf(b2f((u16)r[3])*a0[3]+b0[3],0.f));
        v[4]=(short)f2b(fmaxf(b2f((u16)r[4])*a1[0]+b1[0],0.f));
        v[5]=(short)f2b(fmaxf(b2f((u16)r[5])*a1[1]+b1[1],0.f));
        v[6]=(short)f2b(fmaxf(b2f((u16)r[6])*a1[2]+b1[2],0.f));
        v[7]=(short)f2b(fmaxf(b2f((u16)r[7])*a1[3]+b1[3],0.f));
        *(s16x8*)&lAs[i*2048 + tid*8] = v;
      }
    }
    __syncthreads();                  // drains vmcnt (gld) + lgkm (ds_write)
#pragma unroll
    for (int kk = 0; kk < 64; kk += 32) {
      s16x8 af[4], bf[4];
#pragma unroll
      for (int mi = 0; mi < 4; ++mi) af[mi] = *(const s16x8*)(lA + (mi*16+lr)*64 + kk + lk);
#pragma unroll
      for (int ni = 0; ni < 4; ++ni) bf[ni] = *(const s16x8*)(lB + (ni*16+lr)*64 + kk + lk);
#pragma unroll
      for (int mi = 0; mi < 4; ++mi)
#pragma unroll
        for (int ni = 0; ni < 4; ++ni)
          acc[mi][ni] = __builtin_amdgcn_mfma_f32_16x16x32_bf16(af[mi], bf[ni], acc[mi][ni], 0, 0, 0);
    }
  }

  // C/D frag: col = lane&15, row = (lane>>4)*4 + reg  [m91-verified]
  const int r0 = mblk*128 + wm*64;
  const int c0 = nblk*128 + wn*64;
  const int rr = (lane >> 4) * 4;

  if (EPI == 2) {
    float* Cp = (float*)Cout + (size_t)blockIdx.z * (size_t)M * (size_t)Nn;
#pragma unroll
    for (int mi = 0; mi < 4; ++mi)
#pragma unroll
      for (int ni = 0; ni < 4; ++ni)
#pragma unroll
        for (int r = 0; r < 4; ++r) {
          size_t idx = (size_t)(r0 + mi*16 + rr + r)*ldc + (c0 + ni*16 + lr);
          Cp[idx] += acc[mi][ni][r];
        }
  } else if (EPI == 3) {
    u16* Cp = (u16*)Cout;
#pragma unroll
    for (int mi = 0; mi < 4; ++mi)
#pragma unroll
      for (int ni = 0; ni < 4; ++ni)
#pragma unroll
        for (int r = 0; r < 4; ++r)
          Cp[(size_t)(c0 + ni*16 + lr)*ldc + (r0 + mi*16 + rr + r)] = f2b(acc[mi][ni][r]);
  } else {
    u16* Cp = (u16*)Cout;
    float bv[4];
#pragma unroll
    for (int ni = 0; ni < 4; ++ni)
      bv[ni] = (EPI == 1 && bias) ? bias[c0 + ni*16 + lr] : 0.f;
#pragma unroll
    for (int mi = 0; mi < 4; ++mi)
#pragma unroll
      for (int ni = 0; ni < 4; ++ni)
#pragma unroll
        for (int r = 0; r < 4; ++r) {
          float v = acc[mi][ni][r];
          if (EPI == 1) v = fmaxf(v + bv[ni], 0.f);
          Cp[(size_t)(r0 + mi*16 + rr + r)*ldc + (c0 + ni*16 + lr)] = f2b(v);
        }
  }
  (void)M; (void)Nn;
}

// ---------------------------------------------------------------------------
// rowgemm2 (in-place row-local GEMM, small-ws path):
//   X_stripe[64 rows] = relu( (opt BN) X_stripe @ Bt^T + bias )
// 512 thr / 8 waves (2m x 4n); stripe in 128 KB LDS (XOR swizzle
// col ^= (row&7)<<3); B: col-tiles of 128, K-tiles of 64, double-buffered
// 2x16 KB staged via global_load_lds with pre-swizzled source. Per-col-tile
// epilogue stores to global (input lives in LDS -> in-place race-free).
// LDS total = 160 KB (gfx950 max), 1 block/CU.
// ---------------------------------------------------------------------------
__global__ __launch_bounds__(512, 2)
void rowgemm2(u16* __restrict__ X, const u16* __restrict__ Bt,
              const float* __restrict__ as_, const float* __restrict__ bs_,
              const float* __restrict__ bias)
{
  __shared__ u16 lsA[64*1024];        // 128 KB
  __shared__ u16 lsB[2][128*64];      // 2 x 16 KB
  const int tid = threadIdx.x, wid = tid >> 6, lane = tid & 63;
  const size_t row0 = (size_t)blockIdx.x * 64;
  u16* Xs = X + row0*1024;

  // ---- stage stripe (optional fused BN+relu) ----
#pragma unroll
  for (int i = 0; i < 16; ++i) {
    int idx = i*4096 + tid*8;
    int row = idx >> 10, col = idx & 1023;
    s16x8 v = *(const s16x8*)(Xs + idx);
    if (as_) {
      f32x4 a0 = *(const f32x4*)(as_ + col), a1 = *(const f32x4*)(as_ + col + 4);
      f32x4 b0 = *(const f32x4*)(bs_ + col), b1 = *(const f32x4*)(bs_ + col + 4);
      v[0]=(short)f2b(fmaxf(b2f((u16)v[0])*a0[0]+b0[0],0.f));
      v[1]=(short)f2b(fmaxf(b2f((u16)v[1])*a0[1]+b0[1],0.f));
      v[2]=(short)f2b(fmaxf(b2f((u16)v[2])*a0[2]+b0[2],0.f));
      v[3]=(short)f2b(fmaxf(b2f((u16)v[3])*a0[3]+b0[3],0.f));
      v[4]=(short)f2b(fmaxf(b2f((u16)v[4])*a1[0]+b1[0],0.f));
      v[5]=(short)f2b(fmaxf(b2f((u16)v[5])*a1[1]+b1[1],0.f));
      v[6]=(short)f2b(fmaxf(b2f((u16)v[6])*a1[2]+b1[2],0.f));
      v[7]=(short)f2b(fmaxf(b2f((u16)v[7])*a1[3]+b1[3],0.f));
    }
    *(s16x8*)&lsA[(row << 10) + (col ^ ((row & 7) << 3))] = v;
  }

  const int wm = wid >> 2, wn = wid & 3;      // 2m x 4n
  const int lr = lane & 15, lkj = (lane >> 4) * 8;
  const int r_sub = (lane >> 4) * 4;

  // stage B tile (ct,kt) -> lsB[pb]; wave w covers chunks w*2, w*2+1 (1KB ea)
  // LDS linear [row][64]; source k pre-swizzled so reads use k ^ ((row&7)<<3)
  auto stageB = [&](int ct, int kt, int pb) {
#pragma unroll
    for (int i = 0; i < 2; ++i) {
      int c   = wid*2 + i;
      int row = c*8 + (lane >> 3);
      int kof = ((lane & 7) ^ (lane >> 3)) << 3;
      gld_lds16(Bt + (size_t)(ct*128 + row)*1024 + kt*64 + kof,
                &lsB[pb][c*512]);
    }
  };

  for (int ct = 0; ct < 8; ++ct) {
    f32x4 acc[2][2];
#pragma unroll
    for (int m = 0; m < 2; ++m)
#pragma unroll
      for (int n = 0; n < 2; ++n) acc[m][n] = (f32x4){0.f,0.f,0.f,0.f};

    stageB(ct, 0, 0);
    __syncthreads();                  // drains gld + (ct==0) stripe ds_writes

    for (int kt = 0; kt < 16; ++kt) {
      const int pb = kt & 1;
      if (kt < 15) stageB(ct, kt + 1, pb ^ 1);
#pragma unroll
      for (int kk = 0; kk < 64; kk += 32) {
        s16x8 af[2], bf[2];
#pragma unroll
        for (int m = 0; m < 2; ++m) {
          int row = wm*32 + m*16 + lr;
          int k   = kt*64 + kk + lkj;
          af[m] = *(const s16x8*)&lsA[(row << 10) + (k ^ ((row & 7) << 3))];
        }
#pragma unroll
        for (int n = 0; n < 2; ++n) {
          int brow = wn*32 + n*16 + lr;
          int bk   = kk + lkj;
          bf[n] = *(const s16x8*)&lsB[pb][(brow << 6) + (bk ^ ((brow & 7) << 3))];
        }
#pragma unroll
        for (int m = 0; m < 2; ++m)
#pragma unroll
          for (int n = 0; n < 2; ++n)
            acc[m][n] = __builtin_amdgcn_mfma_f32_16x16x32_bf16(af[m], bf[n], acc[m][n], 0, 0, 0);
      }
      __syncthreads();                // reads of buf[pb] done; buf[pb^1] ready
    }

    // epilogue: store this col-tile (in-place over own rows)
#pragma unroll
    for (int m = 0; m < 2; ++m)
#pragma unroll
      for (int n = 0; n < 2; ++n) {
        const int col = ct*128 + wn*32 + n*16 + lr;
        const float bv = bias ? bias[col] : 0.f;
#pragma unroll
        for (int r = 0; r < 4; ++r) {
          const int row = wm*32 + m*16 + r_sub + r;
          Xs[(size_t)row*1024 + col] = f2b(fmaxf(acc[m][n][r] + bv, 0.f));
        }
      }
  }
}

// --------------------------- prep / elementwise ----------------------------

__global__ void zero_f32(float* __restrict__ p, int n)
{
  int i = blockIdx.x*256 + threadIdx.x;
  if (i < n) p[i] = 0.f;
}

__global__ void transpose_cvt(const float* __restrict__ in, u16* __restrict__ out, int R, int C)
{
  __shared__ float t[32][33];
  const int bc = blockIdx.x*32, br = blockIdx.y*32;
  const int tx = threadIdx.x & 31, ty = threadIdx.x >> 5;
#pragma unroll
  for (int i = 0; i < 4; ++i) t[ty + 8*i][tx] = in[(size_t)(br + ty + 8*i)*C + bc + tx];
  __syncthreads();
#pragma unroll
  for (int i = 0; i < 4; ++i) out[(size_t)(bc + ty + 8*i)*R + br + tx] = f2b(t[tx][ty + 8*i]);
}

__global__ void col_stats(const u16* __restrict__ X, float* __restrict__ sum,
                          float* __restrict__ sumsq, int C, int rpb)
{
  const int t = threadIdx.x;
  const int vc = C >> 8;
  const size_t r0 = (size_t)blockIdx.x * rpb;
  const int c0 = t * vc;
  float s[4] = {0,0,0,0}, q[4] = {0,0,0,0};
  if (vc == 4) {
    for (int r = 0; r < rpb; ++r) {
      u16x4 v = *(const u16x4*)(X + (r0 + r)*C + c0);
#pragma unroll
      for (int j = 0; j < 4; ++j) { float f = b2f(v[j]); s[j] += f; q[j] += f*f; }
    }
  } else {
    for (int r = 0; r < rpb; ++r) {
      u16x2 v = *(const u16x2*)(X + (r0 + r)*C + c0);
#pragma unroll
      for (int j = 0; j < 2; ++j) { float f = b2f(v[j]); s[j] += f; q[j] += f*f; }
    }
  }
  for (int j = 0; j < vc; ++j) {
    atomicAdd(&sum[c0 + j],   s[j]);
    atomicAdd(&sumsq[c0 + j], q[j]);
  }
}

__global__ void bn_finalize(const float* __restrict__ sum, const float* __restrict__ sumsq,
                            const float* __restrict__ g, const float* __restrict__ be,
                            float* __restrict__ a, float* __restrict__ b, int C, float invN)
{
  int c = blockIdx.x*256 + threadIdx.x;
  if (c < C) {
    float mu  = sum[c]*invN;
    float var = sumsq[c]*invN - mu*mu;
    float ac  = g[c]*rsqrtf(var + 1e-5f);
    a[c] = ac;
    b[c] = be[c] - mu*ac;
  }
}

__global__ void transpose_bf16(const u16* __restrict__ in, u16* __restrict__ out, int R, int C)
{
  __shared__ u16 t[64][72];
  const int r0 = blockIdx.x*64, c0 = blockIdx.y*64;
  const int tid = threadIdx.x;
#pragma unroll
  for (int i = 0; i < 2; ++i) {
    int v = i*256 + tid;
    int r = v >> 3, c8 = (v & 7)*8;
    *(s16x8*)&t[r][c8] = *(const s16x8*)&in[(size_t)(r0 + r)*C + c0 + c8];
  }
  __syncthreads();
#pragma unroll
  for (int i = 0; i < 2; ++i) {
    int v = i*256 + tid;
    int c = v >> 3, r8 = (v & 7)*8;
    s16x8 o;
#pragma unroll
    for (int j = 0; j < 8; ++j) o[j] = (short)t[r8 + j][c];
    *(s16x8*)&out[(size_t)(c0 + c)*R + r0 + r8] = o;
  }
}

__global__ void reduce_part(const float* __restrict__ P, float* __restrict__ G, int n, int parts)
{
  int e = blockIdx.x*256 + threadIdx.x;
  if (e < n) {
    float s = 0.f;
    for (int p = 0; p < parts; ++p) s += P[(size_t)p*n + e];
    G[e] = s;
  }
}

__global__ void k_norms(const float* __restrict__ gram, float* __restrict__ norms)
{
  int i = blockIdx.x*256 + threadIdx.x;
  if (i < 1024) norms[i] = sqrtf(fmaxf(gram[(size_t)i*1025], 0.f));
}

__global__ void k_degree(const float* __restrict__ gram, const float* __restrict__ norms,
                         float* __restrict__ dinv)
{
  const int i = blockIdx.x, t = threadIdx.x;
  const float ni = norms[i];
  float p = 0.f;
  for (int j = t; j < 1024; j += 256)
    p += gram[(size_t)i*1024 + j] / (ni*norms[j] + 1e-10f);
#pragma unroll
  for (int o = 32; o; o >>= 1) p += __shfl_down(p, o, 64);
  __shared__ float ws[4];
  if ((t & 63) == 0) ws[t >> 6] = p;
  __syncthreads();
  if (t == 0) {
    float d = ws[0] + ws[1] + ws[2] + ws[3] + 1.0f;
    dinv[i] = d > 0.f ? rsqrtf(d) : 0.f;
  }
}

__global__ void k_sbuild(const float* __restrict__ gram, const float* __restrict__ norms,
                         const float* __restrict__ dinv, u16* __restrict__ Sb)
{
  int e = blockIdx.x*256 + threadIdx.x;
  int i = e >> 10, j = e & 1023;
  float adj = gram[e] / (norms[i]*norms[j] + 1e-10f);
  float a = adj + (i == j ? 1.f : 0.f);
  Sb[e] = f2b(dinv[i]*a*dinv[j]);
}

__global__ void k_sg2t(const u16* __restrict__ SB, const float* __restrict__ GW2,
                       u16* __restrict__ SG2T)
{
  const int t = threadIdx.x;
  const int i = blockIdx.x*16 + (t >> 4);
  const int j = t & 15;
  float acc = 0.f;
  for (int m = 0; m < 1024; ++m) acc += b2f(SB[(size_t)i*1024 + m]) * GW2[m*16 + j];
  SG2T[j*1024 + i] = f2b(acc);
}

__global__ __launch_bounds__(256)
void k_final(const u16* __restrict__ A, const u16* __restrict__ Bt, float* __restrict__ out)
{
  const int wid = threadIdx.x >> 6, lane = threadIdx.x & 63;
  const int r0 = (blockIdx.x*4 + wid) * 16;
  const int lr = lane & 15, lk = (lane >> 4)*8;
  f32x4 acc = (f32x4){0.f,0.f,0.f,0.f};
  const u16* Ab = A  + (size_t)(r0 + lr)*1024 + lk;
  const u16* Bb = Bt + (size_t)lr*1024 + lk;
#pragma unroll 4
  for (int k = 0; k < 1024; k += 32) {
    s16x8 a = *(const s16x8*)(Ab + k);
    s16x8 b = *(const s16x8*)(Bb + k);
    acc = __builtin_amdgcn_mfma_f32_16x16x32_bf16(a, b, acc, 0, 0, 0);
  }
  const int col = lane & 15;
  const int rbase = r0 + (lane >> 4)*4;
#pragma unroll
  for (int r = 0; r < 4; ++r)
    out[(size_t)(rbase + r)*16 + col] = fmaxf(acc[r], 0.f);
}

// ---------------------------------------------------------------------------

extern "C" void kernel_launch(void* const* d_in, const int* in_sizes, int n_in,
                              void* d_out, int out_size, void* d_ws, size_t ws_size,
                              hipStream_t stream)
{
  const float* x   = (const float*)d_in[0];
  const float* W1  = (const float*)d_in[1];
  const float* g1  = (const float*)d_in[3];
  const float* be1 = (const float*)d_in[4];
  const float* W2  = (const float*)d_in[5];
  const float* g2  = (const float*)d_in[7];
  const float* be2 = (const float*)d_in[8];
  const float* W3  = (const float*)d_in[9];
  const float* b3  = (const float*)d_in[10];
  const float* GW1 = (const float*)d_in[11];
  const float* GW2 = (const float*)d_in[12];
  float* outp = (float*)d_out;

  const size_t NEED_S = 215277568ull;     // R4-proven layout
  const size_t NEED_B = 349495296ull;     // out-of-place FC3/GCN1 layout
  char* w = (char*)d_ws;
  const bool BIG = (ws_size >= NEED_B);
  if (!BIG && ws_size < NEED_S) {         // diagnostic clean-fail fallback
    zero_f32<<<4096, 256, 0, stream>>>((float*)d_out, 1048576);
    return;
  }

  // pointer tables (small = R4 layout; big adds separate h3)
  u16 *h1, *h2, *h3, *h3t, *out1;
  float* part;
  char* tail;
  if (BIG) {
    h2   = (u16*)(w);
    h3   = (u16*)(w + 134217728ull);
    h1   = (u16*)(w + 268435456ull);
    h3t  = (u16*)(w + 268435456ull);      // over dead h1
    part = (float*)(w + 301989888ull);
    out1 = (u16*)(w);                     // over dead h2
    tail = w + 335544320ull;
  } else {
    h2   = (u16*)(w);                     // hbuf: h2 -> h3 -> out1 (in-place)
    h3   = (u16*)(w);
    out1 = (u16*)(w);
    h1   = (u16*)(w + 134217728ull);
    h3t  = (u16*)(w + 134217728ull);      // over dead h1
    part = (float*)(w + 167772160ull);
    tail = w + 201326592ull;
  }
  u16*   W1T  = (u16*)(tail);
  u16*   W2T  = (u16*)(tail + 262144);
  u16*   W3T  = (u16*)(tail + 1310720);
  u16*   GW1T = (u16*)(tail + 3407872);
  u16*   SB   = (u16*)(tail + 5505024);
  u16*   SG1T = (u16*)(tail + 7602176);
  u16*   SG2T = (u16*)(tail + 9699328);
  float* GRAM = (float*)(tail + 9732096);
  float* NORMS= (float*)(tail + 13926400);
  float* DINV = (float*)(tail + 13930496);
  float* BNS  = (float*)(tail + 13934592);
  float* BNQ  = (float*)(tail + 13938688);
  float* BNA  = (float*)(tail + 13942784);
  float* BNB  = (float*)(tail + 13946880); // tail end = +13,950,976

  // weight prep
  transpose_cvt<<<dim3(16, 8),  256, 0, stream>>>(W1,  W1T,  256, 512);
  transpose_cvt<<<dim3(32, 16), 256, 0, stream>>>(W2,  W2T,  512, 1024);
  transpose_cvt<<<dim3(32, 32), 256, 0, stream>>>(W3,  W3T,  1024, 1024);
  transpose_cvt<<<dim3(32, 32), 256, 0, stream>>>(GW1, GW1T, 1024, 1024);

  // FC1 (fp32 x) -> h1 raw; stats -> BN1 params (applied in FC2 staging)
  gemm128<0,1><<<dim3(2048,1,1), 256, 0, stream>>>(x, W1T, h1, nullptr, nullptr, nullptr,
      65536, 512, 256, 256, 256, 512, 2);
  zero_f32<<<8, 256, 0, stream>>>(BNS, 2048);       // BNS+BNQ adjacent
  col_stats<<<512, 256, 0, stream>>>(h1, BNS, BNQ, 512, 128);
  bn_finalize<<<2, 256, 0, stream>>>(BNS, BNQ, g1, be1, BNA, BNB, 512, 1.f/65536.f);

  // FC2 (A = BN1+relu(h1), fused) -> h2 raw; stats -> BN2 params
  gemm128<0,2><<<dim3(4096,1,1), 256, 0, stream>>>(h1, W2T, h2, nullptr, BNA, BNB,
      65536, 1024, 512, 512, 512, 1024, 3);
  zero_f32<<<8, 256, 0, stream>>>(BNS, 2048);
  col_stats<<<512, 256, 0, stream>>>(h2, BNS, BNQ, 1024, 128);
  bn_finalize<<<4, 256, 0, stream>>>(BNS, BNQ, g2, be2, BNA, BNB, 1024, 1.f/65536.f);

  // FC3: h3 = relu( (BN2+relu(h2)) @ W3 + b3 )
  if (BIG) {
    gemm128<1,2><<<dim3(4096,1,1), 256, 0, stream>>>(h2, W3T, h3, b3, BNA, BNB,
        65536, 1024, 1024, 1024, 1024, 1024, 3);
  } else {
    rowgemm2<<<1024, 512, 0, stream>>>(h3, W3T, BNA, BNB, b3);  // in-place h2->h3
  }

  // gram = h3^T h3, 4 row-chunks, split-K z=4 into part planes (+=), reduce
  zero_f32<<<16384, 256, 0, stream>>>(part, 4194304);
  for (int c = 0; c < 4; ++c) {
    transpose_bf16<<<dim3(256, 16), 256, 0, stream>>>(h3 + (size_t)c*16384*1024, h3t, 16384, 1024);
    gemm128<2,0><<<dim3(64,1,4), 256, 0, stream>>>(h3t, h3t, part, nullptr, nullptr, nullptr,
        1024, 1024, 4096, 16384, 16384, 1024, 3);
  }
  reduce_part<<<4096, 256, 0, stream>>>(part, GRAM, 1048576, 4);

  // S build + folded weights
  k_norms<<<4, 256, 0, stream>>>(GRAM, NORMS);
  k_degree<<<1024, 256, 0, stream>>>(GRAM, NORMS, DINV);
  k_sbuild<<<4096, 256, 0, stream>>>(GRAM, NORMS, DINV, SB);
  k_sg2t<<<64, 256, 0, stream>>>(SB, GW2, SG2T);
  gemm128<3,0><<<dim3(64,1,1), 256, 0, stream>>>(SB, GW1T, SG1T, nullptr, nullptr, nullptr,
      1024, 1024, 1024, 1024, 1024, 1024, 3);

  // GCN layer 1: out1 = relu(h3 @ SG1)
  if (BIG) {
    gemm128<1,0><<<dim3(4096,1,1), 256, 0, stream>>>(h3, SG1T, out1, nullptr, nullptr, nullptr,
        65536, 1024, 1024, 1024, 1024, 1024, 3);
  } else {
    rowgemm2<<<1024, 512, 0, stream>>>(out1, SG1T, nullptr, nullptr, nullptr); // in-place
  }

  // GCN layer 2: out = relu(out1 @ SG2)
  k_final<<<1024, 256, 0, stream>>>(out1, SG2T, outp);

  (void)in_sizes; (void)n_in; (void)out_size;
}

// Round 6
// 1544.107 us; speedup vs baseline: 1.3031x; 1.0569x over previous
//
#include <hip/hip_runtime.h>
#include <cstddef>
#include <cstdint>

// ---------------------------------------------------------------------------
// FCGCN — R6. R5 passed at 1632 µs; rowgemm2 (2x ~372 µs, 46% of total) was
// occupancy-capped (160KB LDS -> 1 block/CU, 24% occ). This round dissolves
// the in-place constraint via CHUNK SLOT-SHIFTING (no copies):
//   FC3 chunk0 -> tmp(32MB); chunk c -> slot(c-1) (dead input chunk).
//   h3 = {tmp, slot0, slot1, slot2}; GCN1 shifts again -> {slot3, tmp, s0, s1}.
// All big GEMMs now go through the verified gemm128 (4 blocks/CU, 16 waves).
// Gram uses 8 sub-chunks of 8192 rows (16MB transposed scratch) so the peak
// workspace stays EXACTLY at the R4/R5-proven 215,277,568 bytes.
// Algebra: S folded into GW1/GW2; BN biases b1,b2 cancel and are never read;
// BN1/BN2 applied fused in the consumer GEMM's A-staging.
// ---------------------------------------------------------------------------

typedef unsigned short u16;
typedef unsigned int   u32;
typedef __attribute__((ext_vector_type(8))) short  s16x8;
typedef __attribute__((ext_vector_type(4))) float  f32x4;
typedef __attribute__((ext_vector_type(4))) u16    u16x4;
typedef __attribute__((ext_vector_type(2))) u16    u16x2;

__device__ __forceinline__ float b2f(u16 u){ u32 x = ((u32)u)<<16; float f; __builtin_memcpy(&f,&x,4); return f; }
__device__ __forceinline__ u16 f2b(float f){ u32 x; __builtin_memcpy(&x,&f,4); x += 0x7fffu + ((x>>16)&1u); return (u16)(x>>16); }

typedef const __attribute__((address_space(1))) u32* gas1_t;
typedef __attribute__((address_space(3))) u32*       las3_t;
__device__ __forceinline__ void gld_lds16(const void* g, void* l){
  // async global->LDS: per-lane global src, wave-uniform LDS base + lane*16.
  __builtin_amdgcn_global_load_lds((gas1_t)g, (las3_t)l, 16, 0, 0);
}

// ---------------------------------------------------------------------------
// gemm128: C[M,N] = A[M,K] @ Bt[N,K]^T (row-major, K contiguous). 128x128
// tile, BK=64, 256 thr = 4 waves (2x2), each wave 64x64 = 4x4 16x16x32 frags.
// B staged via global_load_lds (width 16). A per AMODE:
//   0: bf16 via global_load_lds; 1: fp32->bf16 cvt (reg path);
//   2: bf16 with fused y=relu(v*as_[k]+bs_[k]) (reg path).
// EPI: 0 bf16 store; 1 bf16 relu(v+bias[col]); 2 fp32 += into z-plane
//      partial (sequential accumulation); 3 bf16 transposed store (C^T).
// [verified R5]
// ---------------------------------------------------------------------------
template<int EPI, int AMODE>
__global__ __launch_bounds__(256)
void gemm128(const void* __restrict__ Ap, const u16* __restrict__ Bt,
             void* __restrict__ Cout, const float* __restrict__ bias,
             const float* __restrict__ as_, const float* __restrict__ bs_,
             int M, int Nn, int ksz, int lda, int ldb, int ldc, int lgn)
{
  __shared__ u16 lAs[128*64];
  __shared__ u16 lBs[128*64];
  const int tid = threadIdx.x, wid = tid >> 6, lane = tid & 63;

  const int nwg  = gridDim.x;
  const int bid  = blockIdx.x;
  const int swz  = (bid & 7) * (nwg >> 3) + (bid >> 3);   // XCD-chunked
  const int nblk = swz & ((1 << lgn) - 1);
  const int mblk = swz >> lgn;
  const int k0   = blockIdx.z * ksz;

  f32x4 acc[4][4];
#pragma unroll
  for (int i = 0; i < 4; ++i)
#pragma unroll
    for (int j = 0; j < 4; ++j) acc[i][j] = (f32x4){0.f,0.f,0.f,0.f};

  const u16*   A16 = (const u16*)Ap   + (size_t)mblk*128*lda + k0;
  const float* A32 = (const float*)Ap + (size_t)mblk*128*lda + k0;
  const u16* Bbase = Bt + (size_t)nblk*128*ldb + k0;
  const int wm = wid >> 1, wn = wid & 1;
  const int lr = lane & 15, lk = (lane >> 4) * 8;
  const u16* lA = &lAs[wm*64*64];
  const u16* lB = &lBs[wn*64*64];
  const int srow = tid >> 3;          // 32 rows per issue, 8 threads/row
  const int scol = (tid & 7) * 8;     // 8 bf16 = 16B per thread

  const int nkt = ksz >> 6;
  for (int kt = 0; kt < nkt; ++kt) {
    __syncthreads();                  // all waves done with prev tile's LDS
    const u16* Bk = Bbase + kt*64;
#pragma unroll
    for (int i = 0; i < 4; ++i)
      gld_lds16(Bk + (size_t)(i*32 + srow)*ldb + scol, &lBs[i*2048 + wid*512]);
    if (AMODE == 0) {
      const u16* Ak = A16 + kt*64;
#pragma unroll
      for (int i = 0; i < 4; ++i)
        gld_lds16(Ak + (size_t)(i*32 + srow)*lda + scol, &lAs[i*2048 + wid*512]);
    } else if (AMODE == 1) {
#pragma unroll
      for (int i = 0; i < 4; ++i) {
        const float* p = A32 + (size_t)(i*32 + srow)*lda + kt*64 + scol;
        f32x4 x0 = *(const f32x4*)p;
        f32x4 x1 = *(const f32x4*)(p + 4);
        s16x8 v;
        v[0]=(short)f2b(x0[0]); v[1]=(short)f2b(x0[1]);
        v[2]=(short)f2b(x0[2]); v[3]=(short)f2b(x0[3]);
        v[4]=(short)f2b(x1[0]); v[5]=(short)f2b(x1[1]);
        v[6]=(short)f2b(x1[2]); v[7]=(short)f2b(x1[3]);
        *(s16x8*)&lAs[i*2048 + tid*8] = v;
      }
    } else {                          // AMODE 2: fused BN+relu on A cols (=k)
      const int cb = k0 + kt*64 + scol;
      f32x4 a0 = *(const f32x4*)(as_ + cb), a1 = *(const f32x4*)(as_ + cb + 4);
      f32x4 b0 = *(const f32x4*)(bs_ + cb), b1 = *(const f32x4*)(bs_ + cb + 4);
#pragma unroll
      for (int i = 0; i < 4; ++i) {
        s16x8 r = *(const s16x8*)(A16 + (size_t)(i*32 + srow)*lda + kt*64 + scol);
        s16x8 v;
        v[0]=(short)f2b(fmaxf(b2f((u16)r[0])*a0[0]+b0[0],0.f));
        v[1]=(short)f2b(fmaxf(b2f((u16)r[1])*a0[1]+b0[1],0.f));
        v[2]=(short)f2b(fmaxf(b2f((u16)r[2])*a0[2]+b0[2],0.f));
        v[3]=(short)f2b(fmaxf(b2f((u16)r[3])*a0[3]+b0[3],0.f));
        v[4]=(short)f2b(fmaxf(b2f((u16)r[4])*a1[0]+b1[0],0.f));
        v[5]=(short)f2b(fmaxf(b2f((u16)r[5])*a1[1]+b1[1],0.f));
        v[6]=(short)f2b(fmaxf(b2f((u16)r[6])*a1[2]+b1[2],0.f));
        v[7]=(short)f2b(fmaxf(b2f((u16)r[7])*a1[3]+b1[3],0.f));
        *(s16x8*)&lAs[i*2048 + tid*8] = v;
      }
    }
    __syncthreads();                  // drains vmcnt (gld) + lgkm (ds_write)
#pragma unroll
    for (int kk = 0; kk < 64; kk += 32) {
      s16x8 af[4], bf[4];
#pragma unroll
      for (int mi = 0; mi < 4; ++mi) af[mi] = *(const s16x8*)(lA + (mi*16+lr)*64 + kk + lk);
#pragma unroll
      for (int ni = 0; ni < 4; ++ni) bf[ni] = *(const s16x8*)(lB + (ni*16+lr)*64 + kk + lk);
#pragma unroll
      for (int mi = 0; mi < 4; ++mi)
#pragma unroll
        for (int ni = 0; ni < 4; ++ni)
          acc[mi][ni] = __builtin_amdgcn_mfma_f32_16x16x32_bf16(af[mi], bf[ni], acc[mi][ni], 0, 0, 0);
    }
  }

  // C/D frag: col = lane&15, row = (lane>>4)*4 + reg  [m91-verified]
  const int r0 = mblk*128 + wm*64;
  const int c0 = nblk*128 + wn*64;
  const int rr = (lane >> 4) * 4;

  if (EPI == 2) {
    float* Cp = (float*)Cout + (size_t)blockIdx.z * (size_t)M * (size_t)Nn;
#pragma unroll
    for (int mi = 0; mi < 4; ++mi)
#pragma unroll
      for (int ni = 0; ni < 4; ++ni)
#pragma unroll
        for (int r = 0; r < 4; ++r) {
          size_t idx = (size_t)(r0 + mi*16 + rr + r)*ldc + (c0 + ni*16 + lr);
          Cp[idx] += acc[mi][ni][r];
        }
  } else if (EPI == 3) {
    u16* Cp = (u16*)Cout;
#pragma unroll
    for (int mi = 0; mi < 4; ++mi)
#pragma unroll
      for (int ni = 0; ni < 4; ++ni)
#pragma unroll
        for (int r = 0; r < 4; ++r)
          Cp[(size_t)(c0 + ni*16 + lr)*ldc + (r0 + mi*16 + rr + r)] = f2b(acc[mi][ni][r]);
  } else {
    u16* Cp = (u16*)Cout;
    float bv[4];
#pragma unroll
    for (int ni = 0; ni < 4; ++ni)
      bv[ni] = (EPI == 1 && bias) ? bias[c0 + ni*16 + lr] : 0.f;
#pragma unroll
    for (int mi = 0; mi < 4; ++mi)
#pragma unroll
      for (int ni = 0; ni < 4; ++ni)
#pragma unroll
        for (int r = 0; r < 4; ++r) {
          float v = acc[mi][ni][r];
          if (EPI == 1) v = fmaxf(v + bv[ni], 0.f);
          Cp[(size_t)(r0 + mi*16 + rr + r)*ldc + (c0 + ni*16 + lr)] = f2b(v);
        }
  }
  (void)M; (void)Nn;
}

// --------------------------- prep / elementwise ----------------------------

__global__ void zero_f32(float* __restrict__ p, int n)
{
  int i = blockIdx.x*256 + threadIdx.x;
  if (i < n) p[i] = 0.f;
}

__global__ void transpose_cvt(const float* __restrict__ in, u16* __restrict__ out, int R, int C)
{
  __shared__ float t[32][33];
  const int bc = blockIdx.x*32, br = blockIdx.y*32;
  const int tx = threadIdx.x & 31, ty = threadIdx.x >> 5;
#pragma unroll
  for (int i = 0; i < 4; ++i) t[ty + 8*i][tx] = in[(size_t)(br + ty + 8*i)*C + bc + tx];
  __syncthreads();
#pragma unroll
  for (int i = 0; i < 4; ++i) out[(size_t)(bc + ty + 8*i)*R + br + tx] = f2b(t[tx][ty + 8*i]);
}

__global__ void col_stats(const u16* __restrict__ X, float* __restrict__ sum,
                          float* __restrict__ sumsq, int C, int rpb)
{
  const int t = threadIdx.x;
  const int vc = C >> 8;
  const size_t r0 = (size_t)blockIdx.x * rpb;
  const int c0 = t * vc;
  float s[4] = {0,0,0,0}, q[4] = {0,0,0,0};
  if (vc == 4) {
    for (int r = 0; r < rpb; ++r) {
      u16x4 v = *(const u16x4*)(X + (r0 + r)*C + c0);
#pragma unroll
      for (int j = 0; j < 4; ++j) { float f = b2f(v[j]); s[j] += f; q[j] += f*f; }
    }
  } else {
    for (int r = 0; r < rpb; ++r) {
      u16x2 v = *(const u16x2*)(X + (r0 + r)*C + c0);
#pragma unroll
      for (int j = 0; j < 2; ++j) { float f = b2f(v[j]); s[j] += f; q[j] += f*f; }
    }
  }
  for (int j = 0; j < vc; ++j) {
    atomicAdd(&sum[c0 + j],   s[j]);
    atomicAdd(&sumsq[c0 + j], q[j]);
  }
}

__global__ void bn_finalize(const float* __restrict__ sum, const float* __restrict__ sumsq,
                            const float* __restrict__ g, const float* __restrict__ be,
                            float* __restrict__ a, float* __restrict__ b, int C, float invN)
{
  int c = blockIdx.x*256 + threadIdx.x;
  if (c < C) {
    float mu  = sum[c]*invN;
    float var = sumsq[c]*invN - mu*mu;
    float ac  = g[c]*rsqrtf(var + 1e-5f);
    a[c] = ac;
    b[c] = be[c] - mu*ac;
  }
}

__global__ void transpose_bf16(const u16* __restrict__ in, u16* __restrict__ out, int R, int C)
{
  __shared__ u16 t[64][72];
  const int r0 = blockIdx.x*64, c0 = blockIdx.y*64;
  const int tid = threadIdx.x;
#pragma unroll
  for (int i = 0; i < 2; ++i) {
    int v = i*256 + tid;
    int r = v >> 3, c8 = (v & 7)*8;
    *(s16x8*)&t[r][c8] = *(const s16x8*)&in[(size_t)(r0 + r)*C + c0 + c8];
  }
  __syncthreads();
#pragma unroll
  for (int i = 0; i < 2; ++i) {
    int v = i*256 + tid;
    int c = v >> 3, r8 = (v & 7)*8;
    s16x8 o;
#pragma unroll
    for (int j = 0; j < 8; ++j) o[j] = (short)t[r8 + j][c];
    *(s16x8*)&out[(size_t)(c0 + c)*R + r0 + r8] = o;
  }
}

__global__ void reduce_part(const float* __restrict__ P, float* __restrict__ G, int n, int parts)
{
  int e = blockIdx.x*256 + threadIdx.x;
  if (e < n) {
    float s = 0.f;
    for (int p = 0; p < parts; ++p) s += P[(size_t)p*n + e];
    G[e] = s;
  }
}

__global__ void k_norms(const float* __restrict__ gram, float* __restrict__ norms)
{
  int i = blockIdx.x*256 + threadIdx.x;
  if (i < 1024) norms[i] = sqrtf(fmaxf(gram[(size_t)i*1025], 0.f));
}

__global__ void k_degree(const float* __restrict__ gram, const float* __restrict__ norms,
                         float* __restrict__ dinv)
{
  const int i = blockIdx.x, t = threadIdx.x;
  const float ni = norms[i];
  float p = 0.f;
  for (int j = t; j < 1024; j += 256)
    p += gram[(size_t)i*1024 + j] / (ni*norms[j] + 1e-10f);
#pragma unroll
  for (int o = 32; o; o >>= 1) p += __shfl_down(p, o, 64);
  __shared__ float ws[4];
  if ((t & 63) == 0) ws[t >> 6] = p;
  __syncthreads();
  if (t == 0) {
    float d = ws[0] + ws[1] + ws[2] + ws[3] + 1.0f;
    dinv[i] = d > 0.f ? rsqrtf(d) : 0.f;
  }
}

__global__ void k_sbuild(const float* __restrict__ gram, const float* __restrict__ norms,
                         const float* __restrict__ dinv, u16* __restrict__ Sb)
{
  int e = blockIdx.x*256 + threadIdx.x;
  int i = e >> 10, j = e & 1023;
  float adj = gram[e] / (norms[i]*norms[j] + 1e-10f);
  float a = adj + (i == j ? 1.f : 0.f);
  Sb[e] = f2b(dinv[i]*a*dinv[j]);
}

__global__ void k_sg2t(const u16* __restrict__ SB, const float* __restrict__ GW2,
                       u16* __restrict__ SG2T)
{
  const int t = threadIdx.x;
  const int i = blockIdx.x*16 + (t >> 4);
  const int j = t & 15;
  float acc = 0.f;
  for (int m = 0; m < 1024; ++m) acc += b2f(SB[(size_t)i*1024 + m]) * GW2[m*16 + j];
  SG2T[j*1024 + i] = f2b(acc);
}

// out[rows,16] = relu(A[rows,1024] @ SG2T^T); one 16x16 tile per wave
__global__ __launch_bounds__(256)
void k_final(const u16* __restrict__ A, const u16* __restrict__ Bt, float* __restrict__ out)
{
  const int wid = threadIdx.x >> 6, lane = threadIdx.x & 63;
  const int r0 = (blockIdx.x*4 + wid) * 16;
  const int lr = lane & 15, lk = (lane >> 4)*8;
  f32x4 acc = (f32x4){0.f,0.f,0.f,0.f};
  const u16* Ab = A  + (size_t)(r0 + lr)*1024 + lk;
  const u16* Bb = Bt + (size_t)lr*1024 + lk;
#pragma unroll 4
  for (int k = 0; k < 1024; k += 32) {
    s16x8 a = *(const s16x8*)(Ab + k);
    s16x8 b = *(const s16x8*)(Bb + k);
    acc = __builtin_amdgcn_mfma_f32_16x16x32_bf16(a, b, acc, 0, 0, 0);
  }
  const int col = lane & 15;
  const int rbase = r0 + (lane >> 4)*4;
#pragma unroll
  for (int r = 0; r < 4; ++r)
    out[(size_t)(rbase + r)*16 + col] = fmaxf(acc[r], 0.f);
}

// ---------------------------------------------------------------------------

extern "C" void kernel_launch(void* const* d_in, const int* in_sizes, int n_in,
                              void* d_out, int out_size, void* d_ws, size_t ws_size,
                              hipStream_t stream)
{
  const float* x   = (const float*)d_in[0];
  const float* W1  = (const float*)d_in[1];
  const float* g1  = (const float*)d_in[3];
  const float* be1 = (const float*)d_in[4];
  const float* W2  = (const float*)d_in[5];
  const float* g2  = (const float*)d_in[7];
  const float* be2 = (const float*)d_in[8];
  const float* W3  = (const float*)d_in[9];
  const float* b3  = (const float*)d_in[10];
  const float* GW1 = (const float*)d_in[11];
  const float* GW2 = (const float*)d_in[12];
  float* outp = (float*)d_out;

  // ---- workspace layout, peak 215,277,568 B (R4/R5-proven) ----
  // [0,128M)     hbuf: 4 slots of 32MB (16384 rows each)
  // [128M,160M)  tmp (32MB chunk home; overlays h1 first half after FC2)
  // [160M,176M)  part (4 fp32 z-planes, 16MB)
  // [176M,192M)  h3t16 (transposed 8192-row sub-chunk, 16MB)
  // [192M,+14M)  tail (weights, S, GRAM, stats)
  // h1 (FC1 out, 64MB) = [128M,192M), dead after FC2.
  const size_t NEED_S = 215277568ull;
  if (ws_size < NEED_S) {                 // diagnostic clean-fail fallback
    zero_f32<<<4096, 256, 0, stream>>>((float*)d_out, 1048576);
    return;
  }
  char* w = (char*)d_ws;
  const size_t CHUNK = 16777216ull;       // 16384*1024 u16 elements
  u16*   hbuf = (u16*)(w);
  u16*   h1   = (u16*)(w + 134217728ull);
  u16*   tmp  = (u16*)(w + 134217728ull);
  float* part = (float*)(w + 167772160ull);
  u16*   h3t16= (u16*)(w + 184549376ull);
  char*  tail = w + 201326592ull;
  u16*   W1T  = (u16*)(tail);
  u16*   W2T  = (u16*)(tail + 262144);
  u16*   W3T  = (u16*)(tail + 1310720);
  u16*   GW1T = (u16*)(tail + 3407872);
  u16*   SB   = (u16*)(tail + 5505024);
  u16*   SG1T = (u16*)(tail + 7602176);
  u16*   SG2T = (u16*)(tail + 9699328);
  float* GRAM = (float*)(tail + 9732096);
  float* NORMS= (float*)(tail + 13926400);
  float* DINV = (float*)(tail + 13930496);
  float* BNS  = (float*)(tail + 13934592);
  float* BNQ  = (float*)(tail + 13938688);
  float* BNA  = (float*)(tail + 13942784);
  float* BNB  = (float*)(tail + 13946880);  // tail end = +13,950,976

  // slot-shifted chunk pointer tables
  u16* h3c[4]   = { tmp,            hbuf,            hbuf + CHUNK,   hbuf + 2*CHUNK };
  u16* h3dst[4] = { tmp,            hbuf,            hbuf + CHUNK,   hbuf + 2*CHUNK };
  u16* o1c[4]   = { hbuf + 3*CHUNK, tmp,             hbuf,           hbuf + CHUNK };
  u16* o1dst[4] = { hbuf + 3*CHUNK, tmp,             hbuf,           hbuf + CHUNK };

  // weight prep
  transpose_cvt<<<dim3(16, 8),  256, 0, stream>>>(W1,  W1T,  256, 512);
  transpose_cvt<<<dim3(32, 16), 256, 0, stream>>>(W2,  W2T,  512, 1024);
  transpose_cvt<<<dim3(32, 32), 256, 0, stream>>>(W3,  W3T,  1024, 1024);
  transpose_cvt<<<dim3(32, 32), 256, 0, stream>>>(GW1, GW1T, 1024, 1024);

  // FC1 (fp32 x) -> h1 raw; stats -> BN1 params (applied in FC2 staging)
  gemm128<0,1><<<dim3(2048,1,1), 256, 0, stream>>>(x, W1T, h1, nullptr, nullptr, nullptr,
      65536, 512, 256, 256, 256, 512, 2);
  zero_f32<<<8, 256, 0, stream>>>(BNS, 2048);       // BNS+BNQ adjacent
  col_stats<<<512, 256, 0, stream>>>(h1, BNS, BNQ, 512, 128);
  bn_finalize<<<2, 256, 0, stream>>>(BNS, BNQ, g1, be1, BNA, BNB, 512, 1.f/65536.f);

  // FC2 (A = BN1+relu(h1), fused) -> hbuf raw; stats -> BN2 params
  gemm128<0,2><<<dim3(4096,1,1), 256, 0, stream>>>(h1, W2T, hbuf, nullptr, BNA, BNB,
      65536, 1024, 512, 512, 512, 1024, 3);
  zero_f32<<<8, 256, 0, stream>>>(BNS, 2048);
  col_stats<<<512, 256, 0, stream>>>(hbuf, BNS, BNQ, 1024, 128);
  bn_finalize<<<4, 256, 0, stream>>>(BNS, BNQ, g2, be2, BNA, BNB, 1024, 1.f/65536.f);

  // FC3, 4 slot-shifted chunks: h3 chunk c = relu(BN2(h2 chunk c) @ W3 + b3)
  // chunk0 -> tmp; chunk c>=1 -> slot(c-1) (its input chunk is already dead)
  for (int c = 0; c < 4; ++c) {
    gemm128<1,2><<<dim3(1024,1,1), 256, 0, stream>>>(
        hbuf + (size_t)c*CHUNK, W3T, h3dst[c], b3, BNA, BNB,
        16384, 1024, 1024, 1024, 1024, 1024, 3);
  }

  // gram = h3^T h3: 8 sub-chunks of 8192 rows, each transposed to h3t16 then
  // split-K z=4 GEMM accumulating (+=) into 4 fp32 part planes
  zero_f32<<<16384, 256, 0, stream>>>(part, 4194304);
  for (int c = 0; c < 4; ++c)
    for (int s = 0; s < 2; ++s) {
      transpose_bf16<<<dim3(128, 16), 256, 0, stream>>>(
          h3c[c] + (size_t)s*8192*1024, h3t16, 8192, 1024);
      gemm128<2,0><<<dim3(64,1,4), 256, 0, stream>>>(h3t16, h3t16, part,
          nullptr, nullptr, nullptr, 1024, 1024, 2048, 8192, 8192, 1024, 3);
    }
  reduce_part<<<4096, 256, 0, stream>>>(part, GRAM, 1048576, 4);

  // S build + folded weights
  k_norms<<<4, 256, 0, stream>>>(GRAM, NORMS);
  k_degree<<<1024, 256, 0, stream>>>(GRAM, NORMS, DINV);
  k_sbuild<<<4096, 256, 0, stream>>>(GRAM, NORMS, DINV, SB);
  k_sg2t<<<64, 256, 0, stream>>>(SB, GW2, SG2T);
  gemm128<3,0><<<dim3(64,1,1), 256, 0, stream>>>(SB, GW1T, SG1T, nullptr, nullptr, nullptr,
      1024, 1024, 1024, 1024, 1024, 1024, 3);

  // GCN1, slot-shifted again: out1 chunk c = relu(h3 chunk c @ SG1)
  // chunk0 -> slot3 (free); chunk1 -> tmp; chunk2 -> slot0; chunk3 -> slot1
  for (int c = 0; c < 4; ++c) {
    gemm128<1,0><<<dim3(1024,1,1), 256, 0, stream>>>(
        h3c[c], SG1T, o1dst[c], nullptr, nullptr, nullptr,
        16384, 1024, 1024, 1024, 1024, 1024, 3);
  }

  // GCN2: out chunk c = relu(out1 chunk c @ SG2)
  for (int c = 0; c < 4; ++c)
    k_final<<<256, 256, 0, stream>>>(o1c[c], SG2T, outp + (size_t)c*16384*16);

  (void)in_sizes; (void)n_in; (void)out_size;
}

// Round 7
// 1186.077 us; speedup vs baseline: 1.6965x; 1.3019x over previous
//
#include <hip/hip_runtime.h>
#include <cstddef>
#include <cstdint>

// ---------------------------------------------------------------------------
// FCGCN — R7. R6 = 1544 µs. Counters: FC2 VALU-bound (VALUBusy 50% vs Mfma
// 21%) from fused-BN staging recomputed x8; gram ~456 µs at 1 block/CU.
// Changes:
//  * BN stats fused into FC1/FC2 EPILOGUE (shfl-reduce + atomicAdd per col);
//    BN applied by separate in-place bn_apply; ALL GEMM staging is now pure
//    global_load_lds (no VALU in staging).
//  * gram: symmetric -> lower-triangle tiles only (36/64), dedicated kernel,
//    z=8 fp32 part planes in free slot3 (non-atomic), full-chunk transposes,
//    mirror pass for the upper triangle.
//  * cvt_x once (xb overlays slot0, dead before FC2 writes hbuf).
//  * k_final4: 4 GCN2 chunk launches merged into one (blockIdx.y).
// Peak workspace unchanged: 215,277,568 B (R4/R5/R6-proven).
// Algebra: S folded into GW1/GW2; BN biases b1,b2 cancel (never read).
// ---------------------------------------------------------------------------

typedef unsigned short u16;
typedef unsigned int   u32;
typedef __attribute__((ext_vector_type(8))) short  s16x8;
typedef __attribute__((ext_vector_type(4))) float  f32x4;

__device__ __forceinline__ float b2f(u16 u){ u32 x = ((u32)u)<<16; float f; __builtin_memcpy(&f,&x,4); return f; }
__device__ __forceinline__ u16 f2b(float f){ u32 x; __builtin_memcpy(&x,&f,4); x += 0x7fffu + ((x>>16)&1u); return (u16)(x>>16); }

typedef const __attribute__((address_space(1))) u32* gas1_t;
typedef __attribute__((address_space(3))) u32*       las3_t;
__device__ __forceinline__ void gld_lds16(const void* g, void* l){
  __builtin_amdgcn_global_load_lds((gas1_t)g, (las3_t)l, 16, 0, 0);
}

// ---------------------------------------------------------------------------
// gemm128: C[M,N] = A[M,K] @ Bt[N,K]^T (bf16 row-major, K contiguous).
// 128x128 tile, BK=64, 256 thr = 4 waves (2x2); both operands staged via
// global_load_lds width-16. EPI: 0 plain bf16; 1 bf16 relu(v+bias[col]);
// 3 bf16 transposed store. STATS: epilogue per-column sum/sumsq atomics
// (raw pre-activation acc, fp32).
// ---------------------------------------------------------------------------
template<int EPI, int STATS>
__global__ __launch_bounds__(256)
void gemm128(const u16* __restrict__ A, const u16* __restrict__ Bt,
             void* __restrict__ Cout, const float* __restrict__ bias,
             float* __restrict__ ssum, float* __restrict__ ssq,
             int ksz, int lda, int ldb, int ldc, int lgn)
{
  __shared__ u16 lAs[128*64];
  __shared__ u16 lBs[128*64];
  const int tid = threadIdx.x, wid = tid >> 6, lane = tid & 63;

  const int nwg  = gridDim.x;
  const int bid  = blockIdx.x;
  const int swz  = (bid & 7) * (nwg >> 3) + (bid >> 3);   // XCD-chunked
  const int nblk = swz & ((1 << lgn) - 1);
  const int mblk = swz >> lgn;

  f32x4 acc[4][4];
#pragma unroll
  for (int i = 0; i < 4; ++i)
#pragma unroll
    for (int j = 0; j < 4; ++j) acc[i][j] = (f32x4){0.f,0.f,0.f,0.f};

  const u16* Abase = A  + (size_t)mblk*128*lda;
  const u16* Bbase = Bt + (size_t)nblk*128*ldb;
  const int wm = wid >> 1, wn = wid & 1;
  const int lr = lane & 15, lk = (lane >> 4) * 8;
  const u16* lA = &lAs[wm*64*64];
  const u16* lB = &lBs[wn*64*64];
  const int srow = tid >> 3;          // 32 rows/issue, 8 thr/row
  const int scol = (tid & 7) * 8;     // 16B per thread

  const int nkt = ksz >> 6;
  for (int kt = 0; kt < nkt; ++kt) {
    __syncthreads();                  // prev tile's LDS reads done
    const u16* Ak = Abase + kt*64;
    const u16* Bk = Bbase + kt*64;
#pragma unroll
    for (int i = 0; i < 4; ++i) {
      gld_lds16(Ak + (size_t)(i*32 + srow)*lda + scol, &lAs[i*2048 + wid*512]);
      gld_lds16(Bk + (size_t)(i*32 + srow)*ldb + scol, &lBs[i*2048 + wid*512]);
    }
    __syncthreads();                  // drains vmcnt -> LDS ready
#pragma unroll
    for (int kk = 0; kk < 64; kk += 32) {
      s16x8 af[4], bf[4];
#pragma unroll
      for (int mi = 0; mi < 4; ++mi) af[mi] = *(const s16x8*)(lA + (mi*16+lr)*64 + kk + lk);
#pragma unroll
      for (int ni = 0; ni < 4; ++ni) bf[ni] = *(const s16x8*)(lB + (ni*16+lr)*64 + kk + lk);
#pragma unroll
      for (int mi = 0; mi < 4; ++mi)
#pragma unroll
        for (int ni = 0; ni < 4; ++ni)
          acc[mi][ni] = __builtin_amdgcn_mfma_f32_16x16x32_bf16(af[mi], bf[ni], acc[mi][ni], 0, 0, 0);
    }
  }

  // C/D frag: col = lane&15, row = (lane>>4)*4 + reg  [m91-verified]
  const int r0 = mblk*128 + wm*64;
  const int c0 = nblk*128 + wn*64;
  const int rr = (lane >> 4) * 4;

  if (STATS) {
    // per-column raw-acc stats: lanes l, l^16, l^32, l^48 share column
#pragma unroll
    for (int ni = 0; ni < 4; ++ni) {
      float s = 0.f, q = 0.f;
#pragma unroll
      for (int mi = 0; mi < 4; ++mi)
#pragma unroll
        for (int r = 0; r < 4; ++r) { float v = acc[mi][ni][r]; s += v; q += v*v; }
      s += __shfl_xor(s, 16, 64); q += __shfl_xor(q, 16, 64);
      s += __shfl_xor(s, 32, 64); q += __shfl_xor(q, 32, 64);
      if ((lane >> 4) == 0) {
        atomicAdd(&ssum[c0 + ni*16 + lr], s);
        atomicAdd(&ssq [c0 + ni*16 + lr], q);
      }
    }
  }

  if (EPI == 3) {
    u16* Cp = (u16*)Cout;
#pragma unroll
    for (int mi = 0; mi < 4; ++mi)
#pragma unroll
      for (int ni = 0; ni < 4; ++ni)
#pragma unroll
        for (int r = 0; r < 4; ++r)
          Cp[(size_t)(c0 + ni*16 + lr)*ldc + (r0 + mi*16 + rr + r)] = f2b(acc[mi][ni][r]);
  } else {
    u16* Cp = (u16*)Cout;
    float bv[4];
#pragma unroll
    for (int ni = 0; ni < 4; ++ni)
      bv[ni] = (EPI == 1 && bias) ? bias[c0 + ni*16 + lr] : 0.f;
#pragma unroll
    for (int mi = 0; mi < 4; ++mi)
#pragma unroll
      for (int ni = 0; ni < 4; ++ni)
#pragma unroll
        for (int r = 0; r < 4; ++r) {
          float v = acc[mi][ni][r];
          if (EPI == 1) v = fmaxf(v + bv[ni], 0.f);
          Cp[(size_t)(r0 + mi*16 + rr + r)*ldc + (c0 + ni*16 + lr)] = f2b(v);
        }
  }
}

// ---------------------------------------------------------------------------
// gram_gemm: lower-triangle tiles of G += T_tile_i @ T_tile_j^T, T=[1024][ld]
// bf16 (transposed h3 chunk). blockIdx.x in [0,36) -> (i,j) with j<=i;
// blockIdx.z in [0,8) -> K-slice into fp32 plane P + z*1M (non-atomic +=,
// sequential chunk launches accumulate).
// ---------------------------------------------------------------------------
__global__ __launch_bounds__(256)
void gram_gemm(const u16* __restrict__ T, float* __restrict__ P, int ld, int ksz)
{
  __shared__ u16 lAs[128*64];
  __shared__ u16 lBs[128*64];
  const int tid = threadIdx.x, wid = tid >> 6, lane = tid & 63;

  const int b = blockIdx.x;
  int i = (int)((sqrtf(8.f*(float)b + 1.f) - 1.f) * 0.5f);
  while ((i+1)*(i+2)/2 <= b) ++i;
  while (i*(i+1)/2 > b) --i;
  const int j = b - i*(i+1)/2;        // j <= i
  const int k0 = blockIdx.z * ksz;

  f32x4 acc[4][4];
#pragma unroll
  for (int a = 0; a < 4; ++a)
#pragma unroll
    for (int c = 0; c < 4; ++c) acc[a][c] = (f32x4){0.f,0.f,0.f,0.f};

  const u16* Abase = T + (size_t)i*128*ld + k0;
  const u16* Bbase = T + (size_t)j*128*ld + k0;
  const int wm = wid >> 1, wn = wid & 1;
  const int lr = lane & 15, lk = (lane >> 4) * 8;
  const u16* lA = &lAs[wm*64*64];
  const u16* lB = &lBs[wn*64*64];
  const int srow = tid >> 3;
  const int scol = (tid & 7) * 8;

  const int nkt = ksz >> 6;
  for (int kt = 0; kt < nkt; ++kt) {
    __syncthreads();
    const u16* Ak = Abase + kt*64;
    const u16* Bk = Bbase + kt*64;
#pragma unroll
    for (int t = 0; t < 4; ++t) {
      gld_lds16(Ak + (size_t)(t*32 + srow)*ld + scol, &lAs[t*2048 + wid*512]);
      gld_lds16(Bk + (size_t)(t*32 + srow)*ld + scol, &lBs[t*2048 + wid*512]);
    }
    __syncthreads();
#pragma unroll
    for (int kk = 0; kk < 64; kk += 32) {
      s16x8 af[4], bf[4];
#pragma unroll
      for (int mi = 0; mi < 4; ++mi) af[mi] = *(const s16x8*)(lA + (mi*16+lr)*64 + kk + lk);
#pragma unroll
      for (int ni = 0; ni < 4; ++ni) bf[ni] = *(const s16x8*)(lB + (ni*16+lr)*64 + kk + lk);
#pragma unroll
      for (int mi = 0; mi < 4; ++mi)
#pragma unroll
        for (int ni = 0; ni < 4; ++ni)
          acc[mi][ni] = __builtin_amdgcn_mfma_f32_16x16x32_bf16(af[mi], bf[ni], acc[mi][ni], 0, 0, 0);
    }
  }

  float* Cp = P + (size_t)blockIdx.z * 1048576ull;
  const int r0 = i*128 + wm*64;
  const int c0 = j*128 + wn*64;
  const int rr = (lane >> 4) * 4;
#pragma unroll
  for (int mi = 0; mi < 4; ++mi)
#pragma unroll
    for (int ni = 0; ni < 4; ++ni)
#pragma unroll
      for (int r = 0; r < 4; ++r) {
        size_t idx = (size_t)(r0 + mi*16 + rr + r)*1024 + (c0 + ni*16 + lr);
        Cp[idx] += acc[mi][ni][r];
      }
}

// --------------------------- prep / elementwise ----------------------------

__global__ void zero_f32(float* __restrict__ p, int n)
{
  int i = blockIdx.x*256 + threadIdx.x;
  if (i < n) p[i] = 0.f;
}

__global__ void transpose_cvt(const float* __restrict__ in, u16* __restrict__ out, int R, int C)
{
  __shared__ float t[32][33];
  const int bc = blockIdx.x*32, br = blockIdx.y*32;
  const int tx = threadIdx.x & 31, ty = threadIdx.x >> 5;
#pragma unroll
  for (int i = 0; i < 4; ++i) t[ty + 8*i][tx] = in[(size_t)(br + ty + 8*i)*C + bc + tx];
  __syncthreads();
#pragma unroll
  for (int i = 0; i < 4; ++i) out[(size_t)(bc + ty + 8*i)*R + br + tx] = f2b(t[tx][ty + 8*i]);
}

__global__ void cvt_x(const float* __restrict__ in, u16* __restrict__ out, size_t n8)
{
  size_t i0 = (size_t)blockIdx.x*blockDim.x + threadIdx.x;
  size_t str = (size_t)gridDim.x*blockDim.x;
  for (size_t v = i0; v < n8; v += str) {
    const float* p = in + v*8;
    f32x4 a = *(const f32x4*)p;
    f32x4 b = *(const f32x4*)(p + 4);
    s16x8 o;
    o[0]=(short)f2b(a[0]); o[1]=(short)f2b(a[1]); o[2]=(short)f2b(a[2]); o[3]=(short)f2b(a[3]);
    o[4]=(short)f2b(b[0]); o[5]=(short)f2b(b[1]); o[6]=(short)f2b(b[2]); o[7]=(short)f2b(b[3]);
    *(s16x8*)(out + v*8) = o;
  }
}

__global__ void bn_finalize(const float* __restrict__ sum, const float* __restrict__ sumsq,
                            const float* __restrict__ g, const float* __restrict__ be,
                            float* __restrict__ a, float* __restrict__ b, int C, float invN)
{
  int c = blockIdx.x*256 + threadIdx.x;
  if (c < C) {
    float mu  = sum[c]*invN;
    float var = sumsq[c]*invN - mu*mu;
    float ac  = g[c]*rsqrtf(var + 1e-5f);
    a[c] = ac;
    b[c] = be[c] - mu*ac;
  }
}

// in-place y = relu(v*a[c]+b[c]) on bf16 [*, C], C power of two
__global__ void bn_apply(u16* __restrict__ X, const float* __restrict__ a,
                         const float* __restrict__ b, size_t n8, int cmask)
{
  size_t i0 = (size_t)blockIdx.x*blockDim.x + threadIdx.x;
  size_t str = (size_t)gridDim.x*blockDim.x;
  for (size_t v = i0; v < n8; v += str) {
    size_t base = v*8;
    int c0 = (int)(base & (size_t)cmask);
    s16x8 x = *(const s16x8*)(X + base);
    s16x8 y;
#pragma unroll
    for (int j = 0; j < 8; ++j) {
      float f = b2f((u16)x[j]) * a[c0 + j] + b[c0 + j];
      y[j] = (short)f2b(fmaxf(f, 0.f));
    }
    *(s16x8*)(X + base) = y;
  }
}

__global__ void transpose_bf16(const u16* __restrict__ in, u16* __restrict__ out, int R, int C)
{
  __shared__ u16 t[64][72];
  const int r0 = blockIdx.x*64, c0 = blockIdx.y*64;
  const int tid = threadIdx.x;
#pragma unroll
  for (int i = 0; i < 2; ++i) {
    int v = i*256 + tid;
    int r = v >> 3, c8 = (v & 7)*8;
    *(s16x8*)&t[r][c8] = *(const s16x8*)&in[(size_t)(r0 + r)*C + c0 + c8];
  }
  __syncthreads();
#pragma unroll
  for (int i = 0; i < 2; ++i) {
    int v = i*256 + tid;
    int c = v >> 3, r8 = (v & 7)*8;
    s16x8 o;
#pragma unroll
    for (int j = 0; j < 8; ++j) o[j] = (short)t[r8 + j][c];
    *(s16x8*)&out[(size_t)(c0 + c)*R + r0 + r8] = o;
  }
}

__global__ void reduce_part(const float* __restrict__ P, float* __restrict__ G, int n, int parts)
{
  int e = blockIdx.x*256 + threadIdx.x;
  if (e < n) {
    float s = 0.f;
    for (int p = 0; p < parts; ++p) s += P[(size_t)p*n + e];
    G[e] = s;
  }
}

// fill upper triangle from lower: G[r][c] = G[c][r] for c > r
__global__ void mirror_up(float* __restrict__ G)
{
  int e = blockIdx.x*256 + threadIdx.x;     // covers 1024*1024
  int r = e >> 10, c = e & 1023;
  if (c > r) G[(size_t)r*1024 + c] = G[(size_t)c*1024 + r];
}

__global__ void k_norms(const float* __restrict__ gram, float* __restrict__ norms)
{
  int i = blockIdx.x*256 + threadIdx.x;
  if (i < 1024) norms[i] = sqrtf(fmaxf(gram[(size_t)i*1025], 0.f));
}

__global__ void k_degree(const float* __restrict__ gram, const float* __restrict__ norms,
                         float* __restrict__ dinv)
{
  const int i = blockIdx.x, t = threadIdx.x;
  const float ni = norms[i];
  float p = 0.f;
  for (int j = t; j < 1024; j += 256)
    p += gram[(size_t)i*1024 + j] / (ni*norms[j] + 1e-10f);
#pragma unroll
  for (int o = 32; o; o >>= 1) p += __shfl_down(p, o, 64);
  __shared__ float ws[4];
  if ((t & 63) == 0) ws[t >> 6] = p;
  __syncthreads();
  if (t == 0) {
    float d = ws[0] + ws[1] + ws[2] + ws[3] + 1.0f;
    dinv[i] = d > 0.f ? rsqrtf(d) : 0.f;
  }
}

__global__ void k_sbuild(const float* __restrict__ gram, const float* __restrict__ norms,
                         const float* __restrict__ dinv, u16* __restrict__ Sb)
{
  int e = blockIdx.x*256 + threadIdx.x;
  int i = e >> 10, j = e & 1023;
  float adj = gram[e] / (norms[i]*norms[j] + 1e-10f);
  float a = adj + (i == j ? 1.f : 0.f);
  Sb[e] = f2b(dinv[i]*a*dinv[j]);
}

__global__ void k_sg2t(const u16* __restrict__ SB, const float* __restrict__ GW2,
                       u16* __restrict__ SG2T)
{
  const int t = threadIdx.x;
  const int i = blockIdx.x*16 + (t >> 4);
  const int j = t & 15;
  float acc = 0.f;
  for (int m = 0; m < 1024; ++m) acc += b2f(SB[(size_t)i*1024 + m]) * GW2[m*16 + j];
  SG2T[j*1024 + i] = f2b(acc);
}

// GCN2 for all 4 chunks in one launch: out rows = relu(A_y @ SG2T^T)
__global__ __launch_bounds__(256)
void k_final4(const u16* __restrict__ A0, const u16* __restrict__ A1,
              const u16* __restrict__ A2, const u16* __restrict__ A3,
              const u16* __restrict__ Bt, float* __restrict__ out)
{
  const int y = blockIdx.y;
  const u16* A = (y == 0) ? A0 : (y == 1) ? A1 : (y == 2) ? A2 : A3;
  float* o = out + (size_t)y * 16384 * 16;
  const int wid = threadIdx.x >> 6, lane = threadIdx.x & 63;
  const int r0 = (blockIdx.x*4 + wid) * 16;
  const int lr = lane & 15, lk = (lane >> 4)*8;
  f32x4 acc = (f32x4){0.f,0.f,0.f,0.f};
  const u16* Ab = A  + (size_t)(r0 + lr)*1024 + lk;
  const u16* Bb = Bt + (size_t)lr*1024 + lk;
#pragma unroll 4
  for (int k = 0; k < 1024; k += 32) {
    s16x8 a = *(const s16x8*)(Ab + k);
    s16x8 b = *(const s16x8*)(Bb + k);
    acc = __builtin_amdgcn_mfma_f32_16x16x32_bf16(a, b, acc, 0, 0, 0);
  }
  const int col = lane & 15;
  const int rbase = r0 + (lane >> 4)*4;
#pragma unroll
  for (int r = 0; r < 4; ++r)
    o[(size_t)(rbase + r)*16 + col] = fmaxf(acc[r], 0.f);
}

// ---------------------------------------------------------------------------

extern "C" void kernel_launch(void* const* d_in, const int* in_sizes, int n_in,
                              void* d_out, int out_size, void* d_ws, size_t ws_size,
                              hipStream_t stream)
{
  const float* x   = (const float*)d_in[0];
  const float* W1  = (const float*)d_in[1];
  const float* g1  = (const float*)d_in[3];
  const float* be1 = (const float*)d_in[4];
  const float* W2  = (const float*)d_in[5];
  const float* g2  = (const float*)d_in[7];
  const float* be2 = (const float*)d_in[8];
  const float* W3  = (const float*)d_in[9];
  const float* b3  = (const float*)d_in[10];
  const float* GW1 = (const float*)d_in[11];
  const float* GW2 = (const float*)d_in[12];
  float* outp = (float*)d_out;

  // ---- workspace layout, peak 215,277,568 B (proven) ----
  // [0,128M)    hbuf: 4 slots of 32MB. xb overlays slot0 (dead before FC2).
  //             slot3 holds gram part planes (8x4MB fp32) until GCN1 c=0.
  // [128M,160M) tmp  (FC3 chunk0 out; overlays dead h1 lower half)
  // [160M,192M) h3t32 (full transposed chunk; overlays dead h1 upper half)
  // [192M,...)  tail: weights + S + GRAM + stats
  const size_t NEED_S = 215277568ull;
  if (ws_size < NEED_S) {
    zero_f32<<<4096, 256, 0, stream>>>((float*)d_out, 1048576);
    return;
  }
  char* w = (char*)d_ws;
  const size_t CHUNK = 16777216ull;       // 16384*1024 u16 elems (32MB)
  u16*   hbuf = (u16*)(w);
  u16*   xb   = (u16*)(w);                // 33.5MB, dead after FC1
  float* part = (float*)(w + 100663296ull);  // slot3: 8 fp32 planes, 32MB
  u16*   h1   = (u16*)(w + 134217728ull); // 67MB, dead after FC2
  u16*   tmp  = (u16*)(w + 134217728ull);
  u16*   h3t32= (u16*)(w + 167772160ull); // 32MB
  char*  tail = w + 201326592ull;
  u16*   W1T  = (u16*)(tail);
  u16*   W2T  = (u16*)(tail + 262144);
  u16*   W3T  = (u16*)(tail + 1310720);
  u16*   GW1T = (u16*)(tail + 3407872);
  u16*   SB   = (u16*)(tail + 5505024);
  u16*   SG1T = (u16*)(tail + 7602176);
  u16*   SG2T = (u16*)(tail + 9699328);
  float* GRAM = (float*)(tail + 9732096);
  float* NORMS= (float*)(tail + 13926400);
  float* DINV = (float*)(tail + 13930496);
  float* BNS  = (float*)(tail + 13934592);
  float* BNQ  = (float*)(tail + 13938688);
  float* BNA  = (float*)(tail + 13942784);
  float* BNB  = (float*)(tail + 13946880);

  // slot-shifted chunk tables (h3: FC3 out; o1: GCN1 out)
  u16* h3c[4] = { tmp,            hbuf,  hbuf + CHUNK, hbuf + 2*CHUNK };
  u16* o1c[4] = { hbuf + 3*CHUNK, tmp,   hbuf,         hbuf + CHUNK };

  // weight prep + x conversion
  transpose_cvt<<<dim3(16, 8),  256, 0, stream>>>(W1,  W1T,  256, 512);
  transpose_cvt<<<dim3(32, 16), 256, 0, stream>>>(W2,  W2T,  512, 1024);
  transpose_cvt<<<dim3(32, 32), 256, 0, stream>>>(W3,  W3T,  1024, 1024);
  transpose_cvt<<<dim3(32, 32), 256, 0, stream>>>(GW1, GW1T, 1024, 1024);
  cvt_x<<<2048, 256, 0, stream>>>(x, xb, 2097152ull);

  // FC1 -> h1 raw (stats fused in epilogue); BN1 params; apply in-place
  zero_f32<<<8, 256, 0, stream>>>(BNS, 2048);       // BNS+BNQ adjacent
  gemm128<0,1><<<dim3(2048,1,1), 256, 0, stream>>>(xb, W1T, h1, nullptr,
      BNS, BNQ, 256, 256, 256, 512, 2);
  bn_finalize<<<2, 256, 0, stream>>>(BNS, BNQ, g1, be1, BNA, BNB, 512, 1.f/65536.f);
  bn_apply<<<2048, 256, 0, stream>>>(h1, BNA, BNB, 4194304ull, 511);

  // FC2 -> hbuf raw (stats fused); BN2 params; apply in-place
  zero_f32<<<8, 256, 0, stream>>>(BNS, 2048);
  gemm128<0,1><<<dim3(4096,1,1), 256, 0, stream>>>(h1, W2T, hbuf, nullptr,
      BNS, BNQ, 512, 512, 512, 1024, 3);
  bn_finalize<<<4, 256, 0, stream>>>(BNS, BNQ, g2, be2, BNA, BNB, 1024, 1.f/65536.f);
  bn_apply<<<2048, 256, 0, stream>>>(hbuf, BNA, BNB, 8388608ull, 1023);

  // FC3, 4 slot-shifted chunks: h3 chunk c = relu(h2bn chunk c @ W3 + b3)
  for (int c = 0; c < 4; ++c)
    gemm128<1,0><<<dim3(1024,1,1), 256, 0, stream>>>(
        hbuf + (size_t)c*CHUNK, W3T, h3c[c], b3, nullptr, nullptr,
        1024, 1024, 1024, 1024, 3);

  // gram: per chunk, full transpose -> triangle gemm (z=8 planes, +=)
  zero_f32<<<32768, 256, 0, stream>>>(part, 8388608);
  for (int c = 0; c < 4; ++c) {
    transpose_bf16<<<dim3(256, 16), 256, 0, stream>>>(h3c[c], h3t32, 16384, 1024);
    gram_gemm<<<dim3(36,1,8), 256, 0, stream>>>(h3t32, part, 16384, 2048);
  }
  reduce_part<<<4096, 256, 0, stream>>>(part, GRAM, 1048576, 8);
  mirror_up<<<4096, 256, 0, stream>>>(GRAM);

  // S build + folded weights
  k_norms<<<4, 256, 0, stream>>>(GRAM, NORMS);
  k_degree<<<1024, 256, 0, stream>>>(GRAM, NORMS, DINV);
  k_sbuild<<<4096, 256, 0, stream>>>(GRAM, NORMS, DINV, SB);
  k_sg2t<<<64, 256, 0, stream>>>(SB, GW2, SG2T);
  gemm128<3,0><<<dim3(64,1,1), 256, 0, stream>>>(SB, GW1T, SG1T, nullptr,
      nullptr, nullptr, 1024, 1024, 1024, 1024, 3);

  // GCN1, slot-shifted: out1 chunk c = relu(h3 chunk c @ SG1)
  for (int c = 0; c < 4; ++c)
    gemm128<1,0><<<dim3(1024,1,1), 256, 0, stream>>>(
        h3c[c], SG1T, o1c[c], nullptr, nullptr, nullptr,
        1024, 1024, 1024, 1024, 3);

  // GCN2, all chunks in one launch
  k_final4<<<dim3(256,4), 256, 0, stream>>>(o1c[0], o1c[1], o1c[2], o1c[3],
      SG2T, outp);

  (void)in_sizes; (void)n_in; (void)out_size;
}

// Round 8
// 1170.016 us; speedup vs baseline: 1.7198x; 1.0137x over previous
//
#include <hip/hip_runtime.h>
#include <cstddef>
#include <cstdint>

// ---------------------------------------------------------------------------
// FCGCN — R8. R7 = 1186 µs. Counters: all big GEMMs sit at ~500 TF with
// MfmaUtil ~23%, occupancy 21%, HBM 18% -> the classic 2-phase barrier stall
// (stage and compute strictly serialized per K-tile). This round applies
// T3's "minimum 2-phase" pipeline to gemm128 and gram_gemm:
//   double-buffered LDS (2x32KB), stage(kt+1) issued BEFORE compute(kt),
//   ONE __syncthreads per K-tile (its vmcnt drain covers stage(kt)).
// Everything else is byte-identical to the passing R7.
// Algebra: S folded into GW1/GW2; BN biases b1,b2 cancel (never read);
// BN stats fused in FC1/FC2 epilogues; peak ws = 215,277,568 B (proven).
// ---------------------------------------------------------------------------

typedef unsigned short u16;
typedef unsigned int   u32;
typedef __attribute__((ext_vector_type(8))) short  s16x8;
typedef __attribute__((ext_vector_type(4))) float  f32x4;

__device__ __forceinline__ float b2f(u16 u){ u32 x = ((u32)u)<<16; float f; __builtin_memcpy(&f,&x,4); return f; }
__device__ __forceinline__ u16 f2b(float f){ u32 x; __builtin_memcpy(&x,&f,4); x += 0x7fffu + ((x>>16)&1u); return (u16)(x>>16); }

typedef const __attribute__((address_space(1))) u32* gas1_t;
typedef __attribute__((address_space(3))) u32*       las3_t;
__device__ __forceinline__ void gld_lds16(const void* g, void* l){
  __builtin_amdgcn_global_load_lds((gas1_t)g, (las3_t)l, 16, 0, 0);
}

// ---------------------------------------------------------------------------
// gemm128: C[M,N] = A[M,K] @ Bt[N,K]^T (bf16 row-major, K contiguous).
// 128x128 tile, BK=64, 256 thr = 4 waves (2x2); both operands staged via
// global_load_lds width-16 into DOUBLE-BUFFERED LDS; stage(kt+1) issued
// before compute(kt) so loads fly under MFMA (drained by next barrier).
// EPI: 0 plain bf16; 1 bf16 relu(v+bias[col]); 3 bf16 transposed store.
// STATS: epilogue per-column sum/sumsq atomics (raw pre-activation acc).
// ---------------------------------------------------------------------------
template<int EPI, int STATS>
__global__ __launch_bounds__(256)
void gemm128(const u16* __restrict__ A, const u16* __restrict__ Bt,
             void* __restrict__ Cout, const float* __restrict__ bias,
             float* __restrict__ ssum, float* __restrict__ ssq,
             int ksz, int lda, int ldb, int ldc, int lgn)
{
  __shared__ u16 lAs[2][128*64];
  __shared__ u16 lBs[2][128*64];
  const int tid = threadIdx.x, wid = tid >> 6, lane = tid & 63;

  const int nwg  = gridDim.x;
  const int bid  = blockIdx.x;
  const int swz  = (bid & 7) * (nwg >> 3) + (bid >> 3);   // XCD-chunked
  const int nblk = swz & ((1 << lgn) - 1);
  const int mblk = swz >> lgn;

  f32x4 acc[4][4];
#pragma unroll
  for (int i = 0; i < 4; ++i)
#pragma unroll
    for (int j = 0; j < 4; ++j) acc[i][j] = (f32x4){0.f,0.f,0.f,0.f};

  const u16* Abase = A  + (size_t)mblk*128*lda;
  const u16* Bbase = Bt + (size_t)nblk*128*ldb;
  const int wm = wid >> 1, wn = wid & 1;
  const int lr = lane & 15, lk = (lane >> 4) * 8;
  const int srow = tid >> 3;          // 32 rows/issue, 8 thr/row
  const int scol = (tid & 7) * 8;     // 16B per thread

  // stage K-tile kt into buffer b (8 async gld issues, no waits here)
  auto stage = [&](int kt, int b) {
    const u16* Ak = Abase + kt*64;
    const u16* Bk = Bbase + kt*64;
#pragma unroll
    for (int i = 0; i < 4; ++i) {
      gld_lds16(Ak + (size_t)(i*32 + srow)*lda + scol, &lAs[b][i*2048 + wid*512]);
      gld_lds16(Bk + (size_t)(i*32 + srow)*ldb + scol, &lBs[b][i*2048 + wid*512]);
    }
  };

  const int nkt = ksz >> 6;
  stage(0, 0);
  for (int kt = 0; kt < nkt; ++kt) {
    const int cur = kt & 1;
    __syncthreads();                  // drains stage(kt); prev reads done
    if (kt + 1 < nkt) stage(kt + 1, cur ^ 1);   // flies under compute(kt)
    const u16* lA = &lAs[cur][wm*64*64];
    const u16* lB = &lBs[cur][wn*64*64];
#pragma unroll
    for (int kk = 0; kk < 64; kk += 32) {
      s16x8 af[4], bf[4];
#pragma unroll
      for (int mi = 0; mi < 4; ++mi) af[mi] = *(const s16x8*)(lA + (mi*16+lr)*64 + kk + lk);
#pragma unroll
      for (int ni = 0; ni < 4; ++ni) bf[ni] = *(const s16x8*)(lB + (ni*16+lr)*64 + kk + lk);
#pragma unroll
      for (int mi = 0; mi < 4; ++mi)
#pragma unroll
        for (int ni = 0; ni < 4; ++ni)
          acc[mi][ni] = __builtin_amdgcn_mfma_f32_16x16x32_bf16(af[mi], bf[ni], acc[mi][ni], 0, 0, 0);
    }
  }

  // C/D frag: col = lane&15, row = (lane>>4)*4 + reg  [m91-verified]
  const int r0 = mblk*128 + wm*64;
  const int c0 = nblk*128 + wn*64;
  const int rr = (lane >> 4) * 4;

  if (STATS) {
    // per-column raw-acc stats: lanes l, l^16, l^32, l^48 share column
#pragma unroll
    for (int ni = 0; ni < 4; ++ni) {
      float s = 0.f, q = 0.f;
#pragma unroll
      for (int mi = 0; mi < 4; ++mi)
#pragma unroll
        for (int r = 0; r < 4; ++r) { float v = acc[mi][ni][r]; s += v; q += v*v; }
      s += __shfl_xor(s, 16, 64); q += __shfl_xor(q, 16, 64);
      s += __shfl_xor(s, 32, 64); q += __shfl_xor(q, 32, 64);
      if ((lane >> 4) == 0) {
        atomicAdd(&ssum[c0 + ni*16 + lr], s);
        atomicAdd(&ssq [c0 + ni*16 + lr], q);
      }
    }
  }

  if (EPI == 3) {
    u16* Cp = (u16*)Cout;
#pragma unroll
    for (int mi = 0; mi < 4; ++mi)
#pragma unroll
      for (int ni = 0; ni < 4; ++ni)
#pragma unroll
        for (int r = 0; r < 4; ++r)
          Cp[(size_t)(c0 + ni*16 + lr)*ldc + (r0 + mi*16 + rr + r)] = f2b(acc[mi][ni][r]);
  } else {
    u16* Cp = (u16*)Cout;
    float bv[4];
#pragma unroll
    for (int ni = 0; ni < 4; ++ni)
      bv[ni] = (EPI == 1 && bias) ? bias[c0 + ni*16 + lr] : 0.f;
#pragma unroll
    for (int mi = 0; mi < 4; ++mi)
#pragma unroll
      for (int ni = 0; ni < 4; ++ni)
#pragma unroll
        for (int r = 0; r < 4; ++r) {
          float v = acc[mi][ni][r];
          if (EPI == 1) v = fmaxf(v + bv[ni], 0.f);
          Cp[(size_t)(r0 + mi*16 + rr + r)*ldc + (c0 + ni*16 + lr)] = f2b(v);
        }
  }
}

// ---------------------------------------------------------------------------
// gram_gemm: lower-triangle tiles of G += T_tile_i @ T_tile_j^T, T=[1024][ld]
// bf16 (transposed h3 chunk). blockIdx.x in [0,36) -> (i,j), j<=i; blockIdx.z
// -> K-slice into fp32 plane P + z*1M (non-atomic +=, sequential launches
// accumulate). Same double-buffered pipeline as gemm128.
// ---------------------------------------------------------------------------
__global__ __launch_bounds__(256)
void gram_gemm(const u16* __restrict__ T, float* __restrict__ P, int ld, int ksz)
{
  __shared__ u16 lAs[2][128*64];
  __shared__ u16 lBs[2][128*64];
  const int tid = threadIdx.x, wid = tid >> 6, lane = tid & 63;

  const int b = blockIdx.x;
  int i = (int)((sqrtf(8.f*(float)b + 1.f) - 1.f) * 0.5f);
  while ((i+1)*(i+2)/2 <= b) ++i;
  while (i*(i+1)/2 > b) --i;
  const int j = b - i*(i+1)/2;        // j <= i
  const int k0 = blockIdx.z * ksz;

  f32x4 acc[4][4];
#pragma unroll
  for (int a = 0; a < 4; ++a)
#pragma unroll
    for (int c = 0; c < 4; ++c) acc[a][c] = (f32x4){0.f,0.f,0.f,0.f};

  const u16* Abase = T + (size_t)i*128*ld + k0;
  const u16* Bbase = T + (size_t)j*128*ld + k0;
  const int wm = wid >> 1, wn = wid & 1;
  const int lr = lane & 15, lk = (lane >> 4) * 8;
  const int srow = tid >> 3;
  const int scol = (tid & 7) * 8;

  auto stage = [&](int kt, int bb) {
    const u16* Ak = Abase + kt*64;
    const u16* Bk = Bbase + kt*64;
#pragma unroll
    for (int t = 0; t < 4; ++t) {
      gld_lds16(Ak + (size_t)(t*32 + srow)*ld + scol, &lAs[bb][t*2048 + wid*512]);
      gld_lds16(Bk + (size_t)(t*32 + srow)*ld + scol, &lBs[bb][t*2048 + wid*512]);
    }
  };

  const int nkt = ksz >> 6;
  stage(0, 0);
  for (int kt = 0; kt < nkt; ++kt) {
    const int cur = kt & 1;
    __syncthreads();
    if (kt + 1 < nkt) stage(kt + 1, cur ^ 1);
    const u16* lA = &lAs[cur][wm*64*64];
    const u16* lB = &lBs[cur][wn*64*64];
#pragma unroll
    for (int kk = 0; kk < 64; kk += 32) {
      s16x8 af[4], bf[4];
#pragma unroll
      for (int mi = 0; mi < 4; ++mi) af[mi] = *(const s16x8*)(lA + (mi*16+lr)*64 + kk + lk);
#pragma unroll
      for (int ni = 0; ni < 4; ++ni) bf[ni] = *(const s16x8*)(lB + (ni*16+lr)*64 + kk + lk);
#pragma unroll
      for (int mi = 0; mi < 4; ++mi)
#pragma unroll
        for (int ni = 0; ni < 4; ++ni)
          acc[mi][ni] = __builtin_amdgcn_mfma_f32_16x16x32_bf16(af[mi], bf[ni], acc[mi][ni], 0, 0, 0);
    }
  }

  float* Cp = P + (size_t)blockIdx.z * 1048576ull;
  const int r0 = i*128 + wm*64;
  const int c0 = j*128 + wn*64;
  const int rr = (lane >> 4) * 4;
#pragma unroll
  for (int mi = 0; mi < 4; ++mi)
#pragma unroll
    for (int ni = 0; ni < 4; ++ni)
#pragma unroll
      for (int r = 0; r < 4; ++r) {
        size_t idx = (size_t)(r0 + mi*16 + rr + r)*1024 + (c0 + ni*16 + lr);
        Cp[idx] += acc[mi][ni][r];
      }
}

// --------------------------- prep / elementwise ----------------------------

__global__ void zero_f32(float* __restrict__ p, int n)
{
  int i = blockIdx.x*256 + threadIdx.x;
  if (i < n) p[i] = 0.f;
}

__global__ void transpose_cvt(const float* __restrict__ in, u16* __restrict__ out, int R, int C)
{
  __shared__ float t[32][33];
  const int bc = blockIdx.x*32, br = blockIdx.y*32;
  const int tx = threadIdx.x & 31, ty = threadIdx.x >> 5;
#pragma unroll
  for (int i = 0; i < 4; ++i) t[ty + 8*i][tx] = in[(size_t)(br + ty + 8*i)*C + bc + tx];
  __syncthreads();
#pragma unroll
  for (int i = 0; i < 4; ++i) out[(size_t)(bc + ty + 8*i)*R + br + tx] = f2b(t[tx][ty + 8*i]);
}

__global__ void cvt_x(const float* __restrict__ in, u16* __restrict__ out, size_t n8)
{
  size_t i0 = (size_t)blockIdx.x*blockDim.x + threadIdx.x;
  size_t str = (size_t)gridDim.x*blockDim.x;
  for (size_t v = i0; v < n8; v += str) {
    const float* p = in + v*8;
    f32x4 a = *(const f32x4*)p;
    f32x4 b = *(const f32x4*)(p + 4);
    s16x8 o;
    o[0]=(short)f2b(a[0]); o[1]=(short)f2b(a[1]); o[2]=(short)f2b(a[2]); o[3]=(short)f2b(a[3]);
    o[4]=(short)f2b(b[0]); o[5]=(short)f2b(b[1]); o[6]=(short)f2b(b[2]); o[7]=(short)f2b(b[3]);
    *(s16x8*)(out + v*8) = o;
  }
}

__global__ void bn_finalize(const float* __restrict__ sum, const float* __restrict__ sumsq,
                            const float* __restrict__ g, const float* __restrict__ be,
                            float* __restrict__ a, float* __restrict__ b, int C, float invN)
{
  int c = blockIdx.x*256 + threadIdx.x;
  if (c < C) {
    float mu  = sum[c]*invN;
    float var = sumsq[c]*invN - mu*mu;
    float ac  = g[c]*rsqrtf(var + 1e-5f);
    a[c] = ac;
    b[c] = be[c] - mu*ac;
  }
}

// in-place y = relu(v*a[c]+b[c]) on bf16 [*, C], C power of two
__global__ void bn_apply(u16* __restrict__ X, const float* __restrict__ a,
                         const float* __restrict__ b, size_t n8, int cmask)
{
  size_t i0 = (size_t)blockIdx.x*blockDim.x + threadIdx.x;
  size_t str = (size_t)gridDim.x*blockDim.x;
  for (size_t v = i0; v < n8; v += str) {
    size_t base = v*8;
    int c0 = (int)(base & (size_t)cmask);
    s16x8 x = *(const s16x8*)(X + base);
    s16x8 y;
#pragma unroll
    for (int j = 0; j < 8; ++j) {
      float f = b2f((u16)x[j]) * a[c0 + j] + b[c0 + j];
      y[j] = (short)f2b(fmaxf(f, 0.f));
    }
    *(s16x8*)(X + base) = y;
  }
}

__global__ void transpose_bf16(const u16* __restrict__ in, u16* __restrict__ out, int R, int C)
{
  __shared__ u16 t[64][72];
  const int r0 = blockIdx.x*64, c0 = blockIdx.y*64;
  const int tid = threadIdx.x;
#pragma unroll
  for (int i = 0; i < 2; ++i) {
    int v = i*256 + tid;
    int r = v >> 3, c8 = (v & 7)*8;
    *(s16x8*)&t[r][c8] = *(const s16x8*)&in[(size_t)(r0 + r)*C + c0 + c8];
  }
  __syncthreads();
#pragma unroll
  for (int i = 0; i < 2; ++i) {
    int v = i*256 + tid;
    int c = v >> 3, r8 = (v & 7)*8;
    s16x8 o;
#pragma unroll
    for (int j = 0; j < 8; ++j) o[j] = (short)t[r8 + j][c];
    *(s16x8*)&out[(size_t)(c0 + c)*R + r0 + r8] = o;
  }
}

__global__ void reduce_part(const float* __restrict__ P, float* __restrict__ G, int n, int parts)
{
  int e = blockIdx.x*256 + threadIdx.x;
  if (e < n) {
    float s = 0.f;
    for (int p = 0; p < parts; ++p) s += P[(size_t)p*n + e];
    G[e] = s;
  }
}

// fill upper triangle from lower: G[r][c] = G[c][r] for c > r
__global__ void mirror_up(float* __restrict__ G)
{
  int e = blockIdx.x*256 + threadIdx.x;     // covers 1024*1024
  int r = e >> 10, c = e & 1023;
  if (c > r) G[(size_t)r*1024 + c] = G[(size_t)c*1024 + r];
}

__global__ void k_norms(const float* __restrict__ gram, float* __restrict__ norms)
{
  int i = blockIdx.x*256 + threadIdx.x;
  if (i < 1024) norms[i] = sqrtf(fmaxf(gram[(size_t)i*1025], 0.f));
}

__global__ void k_degree(const float* __restrict__ gram, const float* __restrict__ norms,
                         float* __restrict__ dinv)
{
  const int i = blockIdx.x, t = threadIdx.x;
  const float ni = norms[i];
  float p = 0.f;
  for (int j = t; j < 1024; j += 256)
    p += gram[(size_t)i*1024 + j] / (ni*norms[j] + 1e-10f);
#pragma unroll
  for (int o = 32; o; o >>= 1) p += __shfl_down(p, o, 64);
  __shared__ float ws[4];
  if ((t & 63) == 0) ws[t >> 6] = p;
  __syncthreads();
  if (t == 0) {
    float d = ws[0] + ws[1] + ws[2] + ws[3] + 1.0f;
    dinv[i] = d > 0.f ? rsqrtf(d) : 0.f;
  }
}

__global__ void k_sbuild(const float* __restrict__ gram, const float* __restrict__ norms,
                         const float* __restrict__ dinv, u16* __restrict__ Sb)
{
  int e = blockIdx.x*256 + threadIdx.x;
  int i = e >> 10, j = e & 1023;
  float adj = gram[e] / (norms[i]*norms[j] + 1e-10f);
  float a = adj + (i == j ? 1.f : 0.f);
  Sb[e] = f2b(dinv[i]*a*dinv[j]);
}

__global__ void k_sg2t(const u16* __restrict__ SB, const float* __restrict__ GW2,
                       u16* __restrict__ SG2T)
{
  const int t = threadIdx.x;
  const int i = blockIdx.x*16 + (t >> 4);
  const int j = t & 15;
  float acc = 0.f;
  for (int m = 0; m < 1024; ++m) acc += b2f(SB[(size_t)i*1024 + m]) * GW2[m*16 + j];
  SG2T[j*1024 + i] = f2b(acc);
}

// GCN2 for all 4 chunks in one launch: out rows = relu(A_y @ SG2T^T)
__global__ __launch_bounds__(256)
void k_final4(const u16* __restrict__ A0, const u16* __restrict__ A1,
              const u16* __restrict__ A2, const u16* __restrict__ A3,
              const u16* __restrict__ Bt, float* __restrict__ out)
{
  const int y = blockIdx.y;
  const u16* A = (y == 0) ? A0 : (y == 1) ? A1 : (y == 2) ? A2 : A3;
  float* o = out + (size_t)y * 16384 * 16;
  const int wid = threadIdx.x >> 6, lane = threadIdx.x & 63;
  const int r0 = (blockIdx.x*4 + wid) * 16;
  const int lr = lane & 15, lk = (lane >> 4)*8;
  f32x4 acc = (f32x4){0.f,0.f,0.f,0.f};
  const u16* Ab = A  + (size_t)(r0 + lr)*1024 + lk;
  const u16* Bb = Bt + (size_t)lr*1024 + lk;
#pragma unroll 4
  for (int k = 0; k < 1024; k += 32) {
    s16x8 a = *(const s16x8*)(Ab + k);
    s16x8 b = *(const s16x8*)(Bb + k);
    acc = __builtin_amdgcn_mfma_f32_16x16x32_bf16(a, b, acc, 0, 0, 0);
  }
  const int col = lane & 15;
  const int rbase = r0 + (lane >> 4)*4;
#pragma unroll
  for (int r = 0; r < 4; ++r)
    o[(size_t)(rbase + r)*16 + col] = fmaxf(acc[r], 0.f);
}

// ---------------------------------------------------------------------------

extern "C" void kernel_launch(void* const* d_in, const int* in_sizes, int n_in,
                              void* d_out, int out_size, void* d_ws, size_t ws_size,
                              hipStream_t stream)
{
  const float* x   = (const float*)d_in[0];
  const float* W1  = (const float*)d_in[1];
  const float* g1  = (const float*)d_in[3];
  const float* be1 = (const float*)d_in[4];
  const float* W2  = (const float*)d_in[5];
  const float* g2  = (const float*)d_in[7];
  const float* be2 = (const float*)d_in[8];
  const float* W3  = (const float*)d_in[9];
  const float* b3  = (const float*)d_in[10];
  const float* GW1 = (const float*)d_in[11];
  const float* GW2 = (const float*)d_in[12];
  float* outp = (float*)d_out;

  // ---- workspace layout, peak 215,277,568 B (proven) ----
  const size_t NEED_S = 215277568ull;
  if (ws_size < NEED_S) {
    zero_f32<<<4096, 256, 0, stream>>>((float*)d_out, 1048576);
    return;
  }
  char* w = (char*)d_ws;
  const size_t CHUNK = 16777216ull;       // 16384*1024 u16 elems (32MB)
  u16*   hbuf = (u16*)(w);
  u16*   xb   = (u16*)(w);                // 33.5MB, dead after FC1
  float* part = (float*)(w + 100663296ull);  // slot3: 8 fp32 planes, 32MB
  u16*   h1   = (u16*)(w + 134217728ull); // 67MB, dead after FC2
  u16*   tmp  = (u16*)(w + 134217728ull);
  u16*   h3t32= (u16*)(w + 167772160ull); // 32MB
  char*  tail = w + 201326592ull;
  u16*   W1T  = (u16*)(tail);
  u16*   W2T  = (u16*)(tail + 262144);
  u16*   W3T  = (u16*)(tail + 1310720);
  u16*   GW1T = (u16*)(tail + 3407872);
  u16*   SB   = (u16*)(tail + 5505024);
  u16*   SG1T = (u16*)(tail + 7602176);
  u16*   SG2T = (u16*)(tail + 9699328);
  float* GRAM = (float*)(tail + 9732096);
  float* NORMS= (float*)(tail + 13926400);
  float* DINV = (float*)(tail + 13930496);
  float* BNS  = (float*)(tail + 13934592);
  float* BNQ  = (float*)(tail + 13938688);
  float* BNA  = (float*)(tail + 13942784);
  float* BNB  = (float*)(tail + 13946880);

  // slot-shifted chunk tables (h3: FC3 out; o1: GCN1 out)
  u16* h3c[4] = { tmp,            hbuf,  hbuf + CHUNK, hbuf + 2*CHUNK };
  u16* o1c[4] = { hbuf + 3*CHUNK, tmp,   hbuf,         hbuf + CHUNK };

  // weight prep + x conversion
  transpose_cvt<<<dim3(16, 8),  256, 0, stream>>>(W1,  W1T,  256, 512);
  transpose_cvt<<<dim3(32, 16), 256, 0, stream>>>(W2,  W2T,  512, 1024);
  transpose_cvt<<<dim3(32, 32), 256, 0, stream>>>(W3,  W3T,  1024, 1024);
  transpose_cvt<<<dim3(32, 32), 256, 0, stream>>>(GW1, GW1T, 1024, 1024);
  cvt_x<<<2048, 256, 0, stream>>>(x, xb, 2097152ull);

  // FC1 -> h1 raw (stats fused in epilogue); BN1 params; apply in-place
  zero_f32<<<8, 256, 0, stream>>>(BNS, 2048);       // BNS+BNQ adjacent
  gemm128<0,1><<<dim3(2048,1,1), 256, 0, stream>>>(xb, W1T, h1, nullptr,
      BNS, BNQ, 256, 256, 256, 512, 2);
  bn_finalize<<<2, 256, 0, stream>>>(BNS, BNQ, g1, be1, BNA, BNB, 512, 1.f/65536.f);
  bn_apply<<<2048, 256, 0, stream>>>(h1, BNA, BNB, 4194304ull, 511);

  // FC2 -> hbuf raw (stats fused); BN2 params; apply in-place
  zero_f32<<<8, 256, 0, stream>>>(BNS, 2048);
  gemm128<0,1><<<dim3(4096,1,1), 256, 0, stream>>>(h1, W2T, hbuf, nullptr,
      BNS, BNQ, 512, 512, 512, 1024, 3);
  bn_finalize<<<4, 256, 0, stream>>>(BNS, BNQ, g2, be2, BNA, BNB, 1024, 1.f/65536.f);
  bn_apply<<<2048, 256, 0, stream>>>(hbuf, BNA, BNB, 8388608ull, 1023);

  // FC3, 4 slot-shifted chunks: h3 chunk c = relu(h2bn chunk c @ W3 + b3)
  for (int c = 0; c < 4; ++c)
    gemm128<1,0><<<dim3(1024,1,1), 256, 0, stream>>>(
        hbuf + (size_t)c*CHUNK, W3T, h3c[c], b3, nullptr, nullptr,
        1024, 1024, 1024, 1024, 3);

  // gram: per chunk, full transpose -> triangle gemm (z=8 planes, +=)
  zero_f32<<<32768, 256, 0, stream>>>(part, 8388608);
  for (int c = 0; c < 4; ++c) {
    transpose_bf16<<<dim3(256, 16), 256, 0, stream>>>(h3c[c], h3t32, 16384, 1024);
    gram_gemm<<<dim3(36,1,8), 256, 0, stream>>>(h3t32, part, 16384, 2048);
  }
  reduce_part<<<4096, 256, 0, stream>>>(part, GRAM, 1048576, 8);
  mirror_up<<<4096, 256, 0, stream>>>(GRAM);

  // S build + folded weights
  k_norms<<<4, 256, 0, stream>>>(GRAM, NORMS);
  k_degree<<<1024, 256, 0, stream>>>(GRAM, NORMS, DINV);
  k_sbuild<<<4096, 256, 0, stream>>>(GRAM, NORMS, DINV, SB);
  k_sg2t<<<64, 256, 0, stream>>>(SB, GW2, SG2T);
  gemm128<3,0><<<dim3(64,1,1), 256, 0, stream>>>(SB, GW1T, SG1T, nullptr,
      nullptr, nullptr, 1024, 1024, 1024, 1024, 3);

  // GCN1, slot-shifted: out1 chunk c = relu(h3 chunk c @ SG1)
  for (int c = 0; c < 4; ++c)
    gemm128<1,0><<<dim3(1024,1,1), 256, 0, stream>>>(
        h3c[c], SG1T, o1c[c], nullptr, nullptr, nullptr,
        1024, 1024, 1024, 1024, 3);

  // GCN2, all chunks in one launch
  k_final4<<<dim3(256,4), 256, 0, stream>>>(o1c[0], o1c[1], o1c[2], o1c[3],
      SG2T, outp);

  (void)in_sizes; (void)n_in; (void)out_size;
}